// Round 5
// baseline (3223.978 us; speedup 1.0000x reference)
//
#include <hip/hip_runtime.h>
#include <cstdint>
#include <cstddef>

#define B_  128
#define P_  196
#define F_  2048
#define H_  512
#define NF_ 512
#define E_  512
#define V_  10000
#define L_  20
#define T_  19
#define NPAD_ 10112            // 79*128 padded V
#define BH_ (B_ * H_)
#define NBLK_ 256

typedef short s8v __attribute__((ext_vector_type(8)));
typedef float f32x4 __attribute__((ext_vector_type(4)));
typedef unsigned short u16x8 __attribute__((ext_vector_type(8)));

__device__ __forceinline__ float sigf(float x) { return 1.0f / (1.0f + expf(-x)); }
__device__ __forceinline__ ushort f2b(float f) {
    unsigned u = __builtin_bit_cast(unsigned, f);
    u += 0x7fff + ((u >> 16) & 1);          // RNE
    return (ushort)(u >> 16);
}
__device__ __forceinline__ float b2f(ushort h) {
    unsigned u = ((unsigned)h) << 16;
    return __builtin_bit_cast(float, u);
}

// ---- device-wide barrier (non-cooperative): monotone counter, no reset ----
// Release: __syncthreads (block stores issued) + __threadfence (device-scope
// writeback) + device-scope atomicAdd. Acquire: spin on atomic read, then
// __threadfence (invalidate L1/L2) + __syncthreads.
// BOUNDED spin: escapes after ~1M backoff rounds (~80 ms) so a broken
// barrier yields a wrong answer + diagnostics, never a GPU hang.
__device__ __forceinline__ void gbar(unsigned* cnt, unsigned target) {
    __syncthreads();
    if (threadIdx.x == 0) {
        __threadfence();
        atomicAdd(cnt, 1u);
        int spins = 0;
        while (atomicAdd(cnt, 0u) < target && spins < (1 << 20)) {
            __builtin_amdgcn_s_sleep(2);
            ++spins;
        }
        __threadfence();
    }
    __syncthreads();
}

// ---------------- zero fill (16B granularity) ----------------
__global__ __launch_bounds__(256)
void zero_buf(float4* __restrict__ p, int n16) {
    int i = blockIdx.x * 256 + threadIdx.x;
    if (i < n16) p[i] = make_float4(0.f, 0.f, 0.f, 0.f);
}

// ---------------- cast fp32 matrix -> bf16 (with optional zero row-padding) ---
__global__ __launch_bounds__(256)
void cast_mat(const float* __restrict__ s, ushort* __restrict__ d,
              long long total, int cols, int sld, int srows) {
    long long i4 = ((long long)blockIdx.x * 256 + threadIdx.x) * 4;
    if (i4 >= total) return;
    int n = (int)(i4 / cols);
    int k = (int)(i4 - (long long)n * cols);
    float4 v = make_float4(0.f, 0.f, 0.f, 0.f);
    if (n < srows) v = *(const float4*)(s + (size_t)n * sld + k);
    ushort4 o;
    o.x = f2b(v.x); o.y = f2b(v.y); o.z = f2b(v.z); o.w = f2b(v.w);
    *(ushort4*)(d + i4) = o;
}

// ------- cast with gate-interleave row permutation: row n' -> src row (n'&3)*H + (n'>>2)
__global__ __launch_bounds__(256)
void cast_perm(const float* __restrict__ s, ushort* __restrict__ d,
               int cols, int sld) {
    int idx = blockIdx.x * 256 + threadIdx.x;   // over 2048*cols/4
    int i4 = idx * 4;
    int n = i4 / cols;
    int k = i4 - n * cols;
    int r = (n & 3) * H_ + (n >> 2);
    float4 v = *(const float4*)(s + (size_t)r * sld + k);
    ushort4 o;
    o.x = f2b(v.x); o.y = f2b(v.y); o.z = f2b(v.z); o.w = f2b(v.w);
    *(ushort4*)(d + (size_t)n * cols + k) = o;
}

__global__ __launch_bounds__(256)
void build_bg(const float* __restrict__ bih, const float* __restrict__ bhh,
              float* __restrict__ bg) {
    int n = blockIdx.x * 256 + threadIdx.x;     // 2048
    int r = (n & 3) * H_ + (n >> 2);
    bg[n] = bih[r] + bhh[r];
}

#define NCP_ (2560 + NPAD_)    // combo(2560) + preds cols = 12672 (bias layout only)
__global__ __launch_bounds__(256)
void build_bcp(const float* __restrict__ bha, const float* __restrict__ bfb,
               const float* __restrict__ bfc, float* __restrict__ bcp) {
    int n = blockIdx.x * 256 + threadIdx.x;
    if (n >= NCP_) return;
    float v;
    if (n < 512) v = bha[n];
    else if (n < 2560) v = bfb[n - 512];
    else { int r = n - 2560; v = (r < V_) ? bfc[r] : 0.0f; }
    bcp[n] = v;
}

// ------- fused: mean over P + cast enc -> bf16 (one fp32 pass) -------
__global__ __launch_bounds__(256)
void mean_cast_kernel(const float* __restrict__ enc, ushort* __restrict__ encb,
                      float* __restrict__ feat) {
    int b = blockIdx.x >> 3;
    int f = ((blockIdx.x & 7) << 8) + threadIdx.x;
    const float* p = enc + (size_t)b * P_ * F_ + f;
    ushort* pb = encb + (size_t)b * P_ * F_ + f;
    float s = 0.0f;
    for (int q = 0; q < P_; q++) {
        float v = p[(size_t)q * F_];
        pb[(size_t)q * F_] = f2b(v);
        s += v;
    }
    feat[b * F_ + f] = s * (1.0f / 196.0f);
}

// ---------------- mean only (fallback) ----------------
__global__ __launch_bounds__(256) void mean_kernel(const float* __restrict__ enc,
                                                   float* __restrict__ feat) {
    int b = blockIdx.x >> 3;
    int f = ((blockIdx.x & 7) << 8) + threadIdx.x;
    const float* p = enc + (size_t)b * P_ * F_ + f;
    float s = 0.0f;
    for (int q = 0; q < P_; q++) s += p[(size_t)q * F_];
    feat[b * F_ + f] = s * (1.0f / 196.0f);
}

// ---------------- embedding gather -> bf16 ----------------
__global__ __launch_bounds__(256) void gather_b(const float* __restrict__ emb,
                                                const int* __restrict__ gt,
                                                ushort* __restrict__ embx) {
    int idx = blockIdx.x * 256 + threadIdx.x;
    int i4 = idx * 4;
    int e = i4 & (E_ - 1);
    int bt = i4 >> 9;
    int b = bt / T_, t = bt - b * T_;
    int tok = gt[b * L_ + t];
    float4 v = *(const float4*)(emb + (size_t)tok * E_ + e);
    ushort4 o;
    o.x = f2b(v.x); o.y = f2b(v.y); o.z = f2b(v.z); o.w = f2b(v.w);
    *(ushort4*)(embx + i4) = o;
}

// ---------------- fp32 GEMM (fallback feat_att only) -------------
__global__ __launch_bounds__(256)
void gemm_biasb(const float* __restrict__ A, int lda,
                const float* __restrict__ W, int ldw,
                const float* __restrict__ bias,
                ushort* __restrict__ C, long long ldc,
                int M, int N, int K) {
    __shared__ float As[16][65];
    __shared__ float Ws[16][65];
    const int tid = threadIdx.x;
    const int m0 = blockIdx.y << 6;
    const int n0 = blockIdx.x << 6;
    const int row = tid >> 2;
    const int kq  = (tid & 3) << 2;
    const int ty = tid >> 4, tx = tid & 15;
    float acc[4][4] = {};
    for (int k0 = 0; k0 < K; k0 += 16) {
        float4 av = make_float4(0.f, 0.f, 0.f, 0.f);
        float4 wv = make_float4(0.f, 0.f, 0.f, 0.f);
        int m = m0 + row;
        if (m < M) av = *(const float4*)(A + (size_t)m * lda + k0 + kq);
        int n = n0 + row;
        if (n < N) wv = *(const float4*)(W + (size_t)n * ldw + k0 + kq);
        __syncthreads();
        As[kq + 0][row] = av.x; As[kq + 1][row] = av.y;
        As[kq + 2][row] = av.z; As[kq + 3][row] = av.w;
        Ws[kq + 0][row] = wv.x; Ws[kq + 1][row] = wv.y;
        Ws[kq + 2][row] = wv.z; Ws[kq + 3][row] = wv.w;
        __syncthreads();
#pragma unroll
        for (int k = 0; k < 16; k++) {
            float a[4], w[4];
#pragma unroll
            for (int i = 0; i < 4; i++) a[i] = As[k][(ty << 2) + i];
#pragma unroll
            for (int j = 0; j < 4; j++) w[j] = Ws[k][(tx << 2) + j];
#pragma unroll
            for (int i = 0; i < 4; i++)
#pragma unroll
                for (int j = 0; j < 4; j++)
                    acc[i][j] = fmaf(a[i], w[j], acc[i][j]);
        }
    }
#pragma unroll
    for (int i = 0; i < 4; i++) {
        int m = m0 + (ty << 2) + i;
        if (m >= M) continue;
#pragma unroll
        for (int j = 0; j < 4; j++) {
            int n = n0 + (tx << 2) + j;
            if (n >= N) continue;
            C[(size_t)m * ldc + n] = f2b(acc[i][j] + bias[n]);
        }
    }
}

// ---------------- bf16 MFMA GEMM (standalone, non-scan) ----------------
enum { MEPI_NONE = 0, MEPI_BIAS = 1, MEPI_BIASB = 2, MEPI_PREDS = 3 };

__device__ __forceinline__ void stage_tile(const ushort* __restrict__ g, int ld,
                                           int row0, int k0, ushort* lds,
                                           int rows, int w, int l) {
    int nchunk = rows >> 4;                  // 1024 B (16 rows) per chunk
    for (int c = w; c < nchunk; c += 4) {
        int flat = c * 1024 + l * 16;
        int r = flat >> 6;
        int ce = (flat & 63) >> 1;
        const ushort* gp = g + (size_t)(row0 + r) * ld + (k0 + ce);
        __builtin_amdgcn_global_load_lds(
            (const __attribute__((address_space(1))) void*)gp,
            (__attribute__((address_space(3))) void*)(lds + c * 512),
            16, 0, 0);
    }
}

template <int BM, int EPI, int DUAL, int SWZ = 0>
__global__ __launch_bounds__(256)
void mfma_gemm(const ushort* __restrict__ A1, int lda1,
               const ushort* __restrict__ W1, int ldw1, int K1,
               const ushort* __restrict__ A2, int lda2,
               const ushort* __restrict__ W2, int ldw2, int K2,
               const float* __restrict__ bias, void* __restrict__ Cout, long long ldc,
               void* __restrict__ Cout2,
               int M, int N,
               const int* __restrict__ clen, int tcur) {
    __shared__ ushort As[BM * 32];
    __shared__ ushort Bs[128 * 32];
    const int tid = threadIdx.x;
    const int w = tid >> 6, l = tid & 63;
    const int wr = w >> 1, wc = w & 1;
    constexpr int WM = BM / 2;
    constexpr int AF = WM / 16;
    int bx = blockIdx.x, by = blockIdx.y;
    if (SWZ) {
        const int gx = gridDim.x;
        const int nwg = gx * gridDim.y;
        const int fid = by * gx + bx;
        const int q = nwg >> 3, r = nwg & 7;
        const int xcd = fid & 7, idx = fid >> 3;
        const int nf = (xcd < r ? xcd * (q + 1)
                                : r * (q + 1) + (xcd - r) * q) + idx;
        bx = nf % gx; by = nf / gx;
    }
    const int m0 = by * BM;
    const int n0 = bx * 128;
    const int lrow = l & 15, lk8 = (l >> 4) * 8;
    const int kz = blockIdx.z, nzz = gridDim.z;

    f32x4 acc[AF][4] = {};

    for (int pass = 0; pass < 1 + DUAL; pass++) {
        const ushort* A = pass ? A2 : A1;
        const ushort* W = pass ? W2 : W1;
        const int lda = pass ? lda2 : lda1;
        const int ldw = pass ? ldw2 : ldw1;
        const int K  = pass ? K2 : K1;
        const int chunk = K / nzz;
        const int kbeg = kz * chunk;
        const int kend = kbeg + chunk;
        for (int k0 = kbeg; k0 < kend; k0 += 32) {
            __syncthreads();
            stage_tile(A, lda, m0, k0, As, BM, w, l);
            stage_tile(W, ldw, n0, k0, Bs, 128, w, l);
            __syncthreads();
            s8v af[AF], bf[4];
#pragma unroll
            for (int i = 0; i < AF; i++)
                af[i] = *(const s8v*)(As + (wr * WM + i * 16 + lrow) * 32 + lk8);
#pragma unroll
            for (int j = 0; j < 4; j++)
                bf[j] = *(const s8v*)(Bs + (wc * 64 + j * 16 + lrow) * 32 + lk8);
#pragma unroll
            for (int i = 0; i < AF; i++)
#pragma unroll
                for (int j = 0; j < 4; j++)
                    acc[i][j] = __builtin_amdgcn_mfma_f32_16x16x32_bf16(
                        af[i], bf[j], acc[i][j], 0, 0, 0);
        }
    }

    float* Cz = (float*)Cout + (size_t)kz * (size_t)M * ldc;   // z-partials (MEPI_NONE)
#pragma unroll
    for (int i = 0; i < AF; i++) {
        int rb = m0 + wr * WM + i * 16 + (l >> 4) * 4;
#pragma unroll
        for (int j = 0; j < 4; j++) {
            int n = n0 + wc * 64 + j * 16 + (l & 15);
            if (n >= N) continue;
#pragma unroll
            for (int r = 0; r < 4; r++) {
                int m = rb + r;
                float v = acc[i][j][r];
                if (EPI == MEPI_NONE) {
                    Cz[(size_t)m * ldc + n] = v;
                } else if (EPI == MEPI_BIAS) {
                    ((float*)Cout)[(size_t)m * ldc + n] = v + bias[n];
                } else if (EPI == MEPI_BIASB) {
                    ((ushort*)Cout)[(size_t)m * ldc + n] = f2b(v + bias[n]);
                } else if (EPI == MEPI_PREDS) {
                    if (n < V_) {
                        int bb = m & (B_ - 1);
                        int tt = m >> 7;
                        float mk = (tt < clen[bb] - 1) ? 1.0f : 0.0f;
                        ((float*)Cout)[((size_t)bb * T_ + tt) * (size_t)V_ + n] =
                            (v + bias[n]) * mk;
                    }
                }
            }
        }
    }
}

// ---------------- h0/c0 finalize ----------------
__global__ __launch_bounds__(256)
void h0c0_final(const float* __restrict__ part,   // 4 x B x 1024
                const float* __restrict__ b0,
                const float* __restrict__ g0,
                const float* __restrict__ bt0,
                float* __restrict__ cbuf, ushort* __restrict__ hb) {
    int idx = blockIdx.x * 256 + threadIdx.x;   // B*512
    int b = idx >> 9, j = idx & 511;
    const float rbn = 1.0f / sqrtf(1.0f + 1e-5f);
    float sh = b0[j], sc = b0[j + 512];
    for (int z = 0; z < 4; z++) {
        sh += part[((size_t)z * B_ + b) * 1024 + j];
        sc += part[((size_t)z * B_ + b) * 1024 + j + 512];
    }
    float hv = g0[j] * (sigf(sh) * rbn) + bt0[j];
    float cv = g0[j + 512] * (sigf(sc) * rbn) + bt0[j + 512];
    cbuf[idx] = cv;
    hb[idx] = f2b(hv);
}

// ================= persistent scan megakernel (manual grid barrier) ========
// Grid = 256 blocks x 256 threads. Phases per step t:
//   attn -> bar -> gates(z=4 partials) -> bar -> lstm -> bar -> combo(t+1)
// All phase work is grid-stride so correctness is grid-size independent.
// LDS: 10 KB union — attn {eS[256],red[256],pc[1024]} / GEMM {As 2KB, Bs 8KB}.

struct ScanArgs {
    const void* encv;          // encb (bf16) or enc (fp32)
    const ushort* fattb;
    float* combo;
    const float* Wv;
    float* out_alpha;
    const int* clen;
    ushort* gctxb;
    const ushort* WihF;        // 2048 x 2048 (gate-perm)
    const ushort* Whh;         // 2048 x 512  (gate-perm)
    float* gatesP;             // 4 x B x 2048
    const float* embprojP;     // B*T x 2048
    const float* bg;           // 2048
    float* cbuf;               // B x 512
    ushort* hall;              // (T+1) x B x 512, zero-init
    const ushort* Wcp;         // NCP x 512 (combo rows 0..2559 used here)
    const float* bcp;          // NCP
    unsigned* bar;             // barrier counter (zeroed per launch)
};

// combo unit u in [0, 20*nyb): C[b,0:2560] = h @ Wcp^T + bcp (BM=32)
__device__ __forceinline__ void combo_unit(float* smem, const ushort* hsrc,
                                           const ushort* Wcp, const float* bcp,
                                           float* combo, int u, int tid) {
    ushort* As = (ushort*)smem;            // 32*32
    ushort* Bs = (ushort*)smem + 1024;     // 128*32
    const int w = tid >> 6, l = tid & 63;
    const int wr = w >> 1, wc = w & 1;
    const int lrow = l & 15, lk8 = (l >> 4) * 8;
    const int bx = u % 20, by = u / 20;
    const int m0 = by * 32, n0 = bx * 128;
    f32x4 acc[4] = {};
    for (int k0 = 0; k0 < 512; k0 += 32) {
        __syncthreads();
        stage_tile(hsrc, 512, m0, k0, As, 32, w, l);
        stage_tile(Wcp, 512, n0, k0, Bs, 128, w, l);
        __syncthreads();
        s8v af = *(const s8v*)(As + (wr * 16 + lrow) * 32 + lk8);
        s8v bf[4];
#pragma unroll
        for (int j = 0; j < 4; j++)
            bf[j] = *(const s8v*)(Bs + (wc * 64 + j * 16 + lrow) * 32 + lk8);
#pragma unroll
        for (int j = 0; j < 4; j++)
            acc[j] = __builtin_amdgcn_mfma_f32_16x16x32_bf16(af, bf[j], acc[j], 0, 0, 0);
    }
    const int rb = m0 + wr * 16 + (l >> 4) * 4;
#pragma unroll
    for (int j = 0; j < 4; j++) {
        int n = n0 + wc * 64 + j * 16 + (l & 15);
#pragma unroll
        for (int r = 0; r < 4; r++)
            combo[(size_t)(rb + r) * 2560 + n] = acc[j][r] + bcp[n];
    }
}

// gates unit u in [0, 16*nyb*4): z-partial of [gctx|h] @ [WihF|Whh]^T (BM=32)
__device__ __forceinline__ void gates_unit(float* smem, const ushort* gctxb,
                                           const ushort* WihF, const ushort* hin,
                                           const ushort* Whh, float* gatesP,
                                           int u, int nyb, int tid) {
    ushort* As = (ushort*)smem;
    ushort* Bs = (ushort*)smem + 1024;
    const int w = tid >> 6, l = tid & 63;
    const int wr = w >> 1, wc = w & 1;
    const int lrow = l & 15, lk8 = (l >> 4) * 8;
    const int bx = u & 15;
    const int rem = u >> 4;
    const int by = rem % nyb, kz = rem / nyb;    // kz in 0..3
    const int m0 = by * 32, n0 = bx * 128;
    f32x4 acc[4] = {};
#pragma unroll
    for (int pass = 0; pass < 2; pass++) {
        const ushort* A = pass ? hin : gctxb;
        const ushort* W = pass ? Whh : WihF;
        const int ld = pass ? 512 : 2048;        // lda == ldw both passes
        const int chunk = (pass ? 512 : 2048) >> 2;
        const int kbeg = kz * chunk;
        for (int k0 = kbeg; k0 < kbeg + chunk; k0 += 32) {
            __syncthreads();
            stage_tile(A, ld, m0, k0, As, 32, w, l);
            stage_tile(W, ld, n0, k0, Bs, 128, w, l);
            __syncthreads();
            s8v af = *(const s8v*)(As + (wr * 16 + lrow) * 32 + lk8);
            s8v bf[4];
#pragma unroll
            for (int j = 0; j < 4; j++)
                bf[j] = *(const s8v*)(Bs + (wc * 64 + j * 16 + lrow) * 32 + lk8);
#pragma unroll
            for (int j = 0; j < 4; j++)
                acc[j] = __builtin_amdgcn_mfma_f32_16x16x32_bf16(af, bf[j], acc[j], 0, 0, 0);
        }
    }
    const int rb = m0 + wr * 16 + (l >> 4) * 4;
#pragma unroll
    for (int j = 0; j < 4; j++) {
        int n = n0 + wc * 64 + j * 16 + (l & 15);
#pragma unroll
        for (int r = 0; r < 4; r++)
            gatesP[((size_t)kz * B_ + (rb + r)) * 2048 + n] = acc[j][r];
    }
}

// attn unit: b = active batch, half = f-half
template <int BF>
__device__ __forceinline__ void attn_unit(float* smem, const ScanArgs& a,
                                          int t, int b, int half, int tid) {
    float* eS  = smem;          // 256
    float* red = smem + 256;    // 256
    float* pc  = smem + 512;    // 1024
    const int w = tid >> 6, l = tid & 63;
    const float* hap = a.combo + (size_t)b * 2560;
    float ha8[8], wv8[8];
#pragma unroll
    for (int i = 0; i < 8; i++) { ha8[i] = hap[l * 8 + i]; wv8[i] = a.Wv[l * 8 + i]; }
    eS[tid] = -1e30f;
    __syncthreads();
    const ushort* fab = a.fattb + (size_t)b * P_ * NF_;
    for (int p = w; p < P_; p += 4) {
        const ushort* fp = fab + (size_t)p * NF_ + l * 8;
        ushort4 u0 = *(const ushort4*)fp;
        ushort4 u1 = *(const ushort4*)(fp + 4);
        float s = 0.0f, v;
        v = b2f(u0.x) + ha8[0]; v = v > 0.f ? v : 0.f; s = fmaf(v, wv8[0], s);
        v = b2f(u0.y) + ha8[1]; v = v > 0.f ? v : 0.f; s = fmaf(v, wv8[1], s);
        v = b2f(u0.z) + ha8[2]; v = v > 0.f ? v : 0.f; s = fmaf(v, wv8[2], s);
        v = b2f(u0.w) + ha8[3]; v = v > 0.f ? v : 0.f; s = fmaf(v, wv8[3], s);
        v = b2f(u1.x) + ha8[4]; v = v > 0.f ? v : 0.f; s = fmaf(v, wv8[4], s);
        v = b2f(u1.y) + ha8[5]; v = v > 0.f ? v : 0.f; s = fmaf(v, wv8[5], s);
        v = b2f(u1.z) + ha8[6]; v = v > 0.f ? v : 0.f; s = fmaf(v, wv8[6], s);
        v = b2f(u1.w) + ha8[7]; v = v > 0.f ? v : 0.f; s = fmaf(v, wv8[7], s);
#pragma unroll
        for (int off = 32; off > 0; off >>= 1) s += __shfl_down(s, off, 64);
        if (l == 0) eS[p] = s;
    }
    __syncthreads();
    float ev = eS[tid];
    red[tid] = ev;
    __syncthreads();
    for (int s = 128; s > 0; s >>= 1) {
        if (tid < s) red[tid] = fmaxf(red[tid], red[tid + s]);
        __syncthreads();
    }
    float mx = red[0];
    __syncthreads();
    float ex = expf(ev - mx);
    red[tid] = ex;
    __syncthreads();
    for (int s = 128; s > 0; s >>= 1) {
        if (tid < s) red[tid] += red[tid + s];
        __syncthreads();
    }
    float inv = 1.0f / red[0];
    float aa = ex * inv;
    __syncthreads();
    eS[tid] = aa;                    // alpha now in LDS
    if (half == 0 && tid < P_) {
        a.out_alpha[((size_t)b * T_ + t) * P_ + tid] = aa;  // active => mask 1
    }
    __syncthreads();

    // context: 128 col-threads x 8 cols, two 98-long p-ranges
    int tl = tid & 127;
    int pr = tid >> 7;                       // 0 or 1
    int pp0 = pr * 98;
    int f0 = (half << 10) + tl * 8;
    float s[8] = {};
    if (BF) {
        const ushort* ep = (const ushort*)a.encv + (size_t)b * P_ * F_ +
                           (size_t)pp0 * F_ + f0;
        for (int p = 0; p < 98; p++) {
            u16x8 u = *(const u16x8*)(ep + (size_t)p * F_);
            float al = eS[pp0 + p];
#pragma unroll
            for (int i = 0; i < 8; i++) s[i] = fmaf(al, b2f(u[i]), s[i]);
        }
    } else {
        const float* ep = (const float*)a.encv + (size_t)b * P_ * F_ +
                          (size_t)pp0 * F_ + f0;
        for (int p = 0; p < 98; p++) {
            float4 u0 = *(const float4*)(ep + (size_t)p * F_);
            float4 u1 = *(const float4*)(ep + (size_t)p * F_ + 4);
            float al = eS[pp0 + p];
            s[0] = fmaf(al, u0.x, s[0]); s[1] = fmaf(al, u0.y, s[1]);
            s[2] = fmaf(al, u0.z, s[2]); s[3] = fmaf(al, u0.w, s[3]);
            s[4] = fmaf(al, u1.x, s[4]); s[5] = fmaf(al, u1.y, s[5]);
            s[6] = fmaf(al, u1.z, s[6]); s[7] = fmaf(al, u1.w, s[7]);
        }
    }
    if (pr) {
#pragma unroll
        for (int i = 0; i < 8; i++) pc[tl * 8 + i] = s[i];
    }
    __syncthreads();
    if (!pr) {
        const float* gp = a.combo + (size_t)b * 2560 + 512 + f0;
        float4 ga = *(const float4*)gp;
        float4 gb = *(const float4*)(gp + 4);
        float gv[8] = {ga.x, ga.y, ga.z, ga.w, gb.x, gb.y, gb.z, gb.w};
        ushort o[8];
#pragma unroll
        for (int i = 0; i < 8; i++)
            o[i] = f2b(sigf(gv[i]) * (s[i] + pc[tl * 8 + i]));
        *(u16x8*)(a.gctxb + (size_t)b * F_ + f0) = *(u16x8*)o;
    }
    __syncthreads();                 // smem safe for next grid-stride unit
}

template <int BF>
__global__ __launch_bounds__(256, 2)
void scan_mega(ScanArgs a) {
    const int bid = blockIdx.x;
    const int tid = threadIdx.x;
    const int l = tid & 63;
    __shared__ __align__(16) float smem[2560];   // 10 KB phase union
    const int cl1 = a.clen[l] - 1;
    const int cl2 = a.clen[64 + l] - 1;
    unsigned tgt = 0;

    // combo(0): all 128 batches active (clen >= 2)
    for (int u = bid; u < 80; u += NBLK_)
        combo_unit(smem, a.hall, a.Wcp, a.bcp, a.combo, u, tid);

    for (int t = 0; t < T_; t++) {
        unsigned long long m1 = __ballot(t < cl1);
        unsigned long long m2 = __ballot(t < cl2);
        const int na = __popcll(m1) + __popcll(m2);     // active prefix size
        const int nyb = (na + 31) >> 5;

        tgt += NBLK_; gbar(a.bar, tgt);                 // combo ready
        for (int u = bid; u < 2 * na; u += NBLK_)
            attn_unit<BF>(smem, a, t, u >> 1, u & 1, tid);
        tgt += NBLK_; gbar(a.bar, tgt);                 // gctxb ready
        for (int u = bid; u < 16 * nyb * 4; u += NBLK_)
            gates_unit(smem, a.gctxb, a.WihF, a.hall + (size_t)t * BH_,
                       a.Whh, a.gatesP, u, nyb, tid);
        tgt += NBLK_; gbar(a.bar, tgt);                 // gatesP ready
        for (int u = bid; u < 2 * na; u += NBLK_) {
            int idx = u * 256 + tid;                    // b < na guaranteed
            int b = idx >> 9, j = idx & (H_ - 1);
            int n0 = j * 4;
            float4 g = *(const float4*)(a.embprojP + ((size_t)b * T_ + t) * 2048 + n0);
            float4 bgv = *(const float4*)(a.bg + n0);
            g.x += bgv.x; g.y += bgv.y; g.z += bgv.z; g.w += bgv.w;
#pragma unroll
            for (int z = 0; z < 4; z++) {
                float4 p = *(const float4*)(a.gatesP + ((size_t)z * B_ + b) * 2048 + n0);
                g.x += p.x; g.y += p.y; g.z += p.z; g.w += p.w;
            }
            float cn = sigf(g.y) * a.cbuf[idx] + sigf(g.x) * tanhf(g.z);
            float hn = sigf(g.w) * tanhf(cn);
            a.cbuf[idx] = cn;
            (a.hall + (size_t)(t + 1) * BH_)[idx] = f2b(hn);
        }
        if (t + 1 < T_) {
            tgt += NBLK_; gbar(a.bar, tgt);             // hall[t+1] ready
            unsigned long long n1 = __ballot(t + 1 < cl1);
            unsigned long long n2 = __ballot(t + 1 < cl2);
            const int na2 = __popcll(n1) + __popcll(n2);
            const int nyb2 = (na2 + 31) >> 5;
            for (int u = bid; u < 20 * nyb2; u += NBLK_)
                combo_unit(smem, a.hall + (size_t)(t + 1) * BH_, a.Wcp, a.bcp,
                           a.combo, u, tid);
        }
    }
}

extern "C" void kernel_launch(void* const* d_in, const int* in_sizes, int n_in,
                              void* d_out, int out_size, void* d_ws, size_t ws_size,
                              hipStream_t stream) {
    const float* enc = (const float*)d_in[0];
    const float* emb = (const float*)d_in[1];
    const float* Wfa = (const float*)d_in[2];
    const float* bfa = (const float*)d_in[3];
    const float* Wha = (const float*)d_in[4];
    const float* bha = (const float*)d_in[5];
    const float* Wv  = (const float*)d_in[6];
    const float* Wh0 = (const float*)d_in[8];
    const float* bh0 = (const float*)d_in[9];
    const float* Wc0 = (const float*)d_in[10];
    const float* bc0 = (const float*)d_in[11];
    const float* gh  = (const float*)d_in[12];
    const float* bth = (const float*)d_in[13];
    const float* gc  = (const float*)d_in[14];
    const float* btc = (const float*)d_in[15];
    const float* Wfb = (const float*)d_in[16];
    const float* bfb = (const float*)d_in[17];
    const float* Wih = (const float*)d_in[18];
    const float* Whh = (const float*)d_in[19];
    const float* bih = (const float*)d_in[20];
    const float* bhh = (const float*)d_in[21];
    const float* Wfc = (const float*)d_in[22];
    const float* bfc = (const float*)d_in[23];
    const int* gt   = (const int*)d_in[24];
    const int* clen = (const int*)d_in[25];

    float* out_pred  = (float*)d_out;                       // (B,T,V)
    float* out_alpha = out_pred + (size_t)B_ * T_ * V_;     // (B,T,P)

    char* wp = (char*)d_ws;
    auto alloc = [&](size_t bytes) {
        char* p = wp;
        wp += (bytes + 255) & ~(size_t)255;
        return p;
    };
    float*  feat     = (float*)alloc((size_t)B_ * F_ * 4);
    float*  cbuf     = (float*)alloc((size_t)B_ * H_ * 4);
    float*  combo    = (float*)alloc((size_t)B_ * 2560 * 4);
    float*  embprojP = (float*)alloc((size_t)B_ * T_ * 2048 * 4);
    float*  gatesP   = (float*)alloc((size_t)4 * B_ * 2048 * 4);
    float*  hcpart   = (float*)alloc((size_t)4 * B_ * 1024 * 4);
    float*  bcp      = (float*)alloc((size_t)NCP_ * 4);
    float*  bg       = (float*)alloc(2048 * 4);
    float*  b0comb   = (float*)alloc(1024 * 4);
    float*  g0comb   = (float*)alloc(1024 * 4);
    float*  bt0comb  = (float*)alloc(1024 * 4);
    unsigned* barbuf = (unsigned*)alloc(256);
    ushort* hall     = (ushort*)alloc((size_t)(T_ + 1) * B_ * H_ * 2); // h_0..h_T
    ushort* gctxb    = (ushort*)alloc((size_t)B_ * F_ * 2);
    ushort* embxb    = (ushort*)alloc((size_t)B_ * T_ * E_ * 2);
    ushort* fattb    = (ushort*)alloc((size_t)B_ * P_ * NF_ * 2);
    ushort* featb    = (ushort*)alloc((size_t)B_ * F_ * 2);
    ushort* Wfab     = (ushort*)alloc((size_t)NF_ * F_ * 2);
    ushort* WihEbP   = (ushort*)alloc((size_t)2048 * E_ * 2);
    ushort* WihFbP   = (ushort*)alloc((size_t)2048 * F_ * 2);
    ushort* WhhbP    = (ushort*)alloc((size_t)2048 * H_ * 2);
    ushort* Wcp      = (ushort*)alloc((size_t)NCP_ * H_ * 2);
    ushort* W0comb   = (ushort*)alloc((size_t)1024 * F_ * 2);
    ushort* encb     = (ushort*)alloc((size_t)B_ * P_ * F_ * 2);
    const bool big = ((size_t)(wp - (char*)d_ws) <= ws_size);

    auto castM = [&](const float* s, ushort* d, long long rows, int cols, int sld, int srows) {
        long long total = rows * (long long)cols;
        cast_mat<<<(int)((total + 1023) / 1024), 256, 0, stream>>>(s, d, total, cols, sld, srows);
    };

    // ---- zero-init: hall, out_alpha, barrier counter ----
    {
        int n16h = (int)(((size_t)(T_ + 1) * B_ * H_ * 2) / 16);
        zero_buf<<<(n16h + 255) / 256, 256, 0, stream>>>((float4*)hall, n16h);
        int n16a = (int)(((size_t)B_ * T_ * P_ * 4) / 16);
        zero_buf<<<(n16a + 255) / 256, 256, 0, stream>>>((float4*)out_alpha, n16a);
        zero_buf<<<1, 256, 0, stream>>>((float4*)barbuf, 16);
    }

    // ---- one-time casts / permutes / bias builds ----
    castM(Wfa, Wfab, NF_, F_, F_, NF_);
    cast_perm<<<(2048 * E_) / 1024, 256, 0, stream>>>(Wih, WihEbP, E_, E_ + F_);
    cast_perm<<<(2048 * F_) / 1024, 256, 0, stream>>>(Wih + E_, WihFbP, F_, E_ + F_);
    cast_perm<<<(2048 * H_) / 1024, 256, 0, stream>>>(Whh, WhhbP, H_, H_);
    castM(Wha, Wcp, NF_, H_, H_, NF_);
    castM(Wfb, Wcp + (size_t)512 * H_, F_, H_, H_, F_);
    castM(Wfc, Wcp + (size_t)2560 * H_, NPAD_, H_, H_, V_);
    castM(Wh0, W0comb, H_, F_, F_, H_);
    castM(Wc0, W0comb + (size_t)H_ * F_, H_, F_, F_, H_);
    build_bg<<<2048 / 256, 256, 0, stream>>>(bih, bhh, bg);
    build_bcp<<<(NCP_ + 255) / 256, 256, 0, stream>>>(bha, bfb, bfc, bcp);
    hipMemcpyAsync(b0comb, bh0, H_ * 4, hipMemcpyDeviceToDevice, stream);
    hipMemcpyAsync(b0comb + H_, bc0, H_ * 4, hipMemcpyDeviceToDevice, stream);
    hipMemcpyAsync(g0comb, gh, H_ * 4, hipMemcpyDeviceToDevice, stream);
    hipMemcpyAsync(g0comb + H_, gc, H_ * 4, hipMemcpyDeviceToDevice, stream);
    hipMemcpyAsync(bt0comb, bth, H_ * 4, hipMemcpyDeviceToDevice, stream);
    hipMemcpyAsync(bt0comb + H_, btc, H_ * 4, hipMemcpyDeviceToDevice, stream);

    // ---- init state: fused mean+cast ----
    if (big) mean_cast_kernel<<<B_ * 8, 256, 0, stream>>>(enc, encb, feat);
    else     mean_kernel<<<B_ * 8, 256, 0, stream>>>(enc, feat);
    castM(feat, featb, B_, F_, F_, B_);
    mfma_gemm<32, MEPI_NONE, 0><<<dim3(1024 / 128, B_ / 32, 4), 256, 0, stream>>>(
        featb, F_, W0comb, F_, F_, nullptr, 0, nullptr, 0, 0,
        nullptr, hcpart, 1024, nullptr, B_, 1024, nullptr, 0);
    h0c0_final<<<(B_ * H_) / 256, 256, 0, stream>>>(hcpart, b0comb, g0comb, bt0comb, cbuf, hall);
    gather_b<<<(B_ * T_ * E_) / 1024, 256, 0, stream>>>(emb, gt, embxb);

    // ---- feat_att (bf16 out), XCD-swizzled ----
    if (big) {
        mfma_gemm<128, MEPI_BIASB, 0, 1><<<dim3(NF_ / 128, (B_ * P_) / 128, 1), 256, 0, stream>>>(
            encb, F_, Wfab, F_, F_, nullptr, 0, nullptr, 0, 0,
            bfa, fattb, NF_, nullptr, B_ * P_, NF_, nullptr, 0);
    } else {
        gemm_biasb<<<dim3(NF_ / 64, (B_ * P_) / 64), 256, 0, stream>>>(
            enc, F_, Wfa, F_, bfa, fattb, NF_, B_ * P_, NF_, F_);
    }
    // ---- embprojP = embx @ WihEbP^T (fp32, gate-interleaved cols) ----
    mfma_gemm<128, MEPI_NONE, 0><<<dim3(2048 / 128, (B_ * T_) / 128, 1), 256, 0, stream>>>(
        embxb, E_, WihEbP, E_, E_, nullptr, 0, nullptr, 0, 0,
        nullptr, embprojP, 2048, nullptr, B_ * T_, 2048, nullptr, 0);

    // ---- whole recurrent scan: ONE persistent kernel, manual grid barrier ----
    {
        ScanArgs sa;
        sa.encv = big ? (const void*)encb : (const void*)enc;
        sa.fattb = fattb;
        sa.combo = combo;
        sa.Wv = Wv;
        sa.out_alpha = out_alpha;
        sa.clen = clen;
        sa.gctxb = gctxb;
        sa.WihF = WihFbP;
        sa.Whh = WhhbP;
        sa.gatesP = gatesP;
        sa.embprojP = embprojP;
        sa.bg = bg;
        sa.cbuf = cbuf;
        sa.hall = hall;
        sa.Wcp = Wcp;
        sa.bcp = bcp;
        sa.bar = barbuf;
        if (big) scan_mega<1><<<NBLK_, 256, 0, stream>>>(sa);
        else     scan_mega<0><<<NBLK_, 256, 0, stream>>>(sa);
    }

    // ---- deferred predictions: one big GEMM over all (t,b) rows ----
    // A rows m = t*128 + b -> hall slot t+1; masked rows are zero => output 0.
    mfma_gemm<128, MEPI_PREDS, 0, 1><<<dim3(NPAD_ / 128, (B_ * T_) / 128, 1), 256, 0, stream>>>(
        hall + (size_t)B_ * H_, H_, Wcp + (size_t)2560 * H_, H_, H_,
        nullptr, 0, nullptr, 0, 0,
        bcp + 2560, out_pred, V_, nullptr, B_ * T_, NPAD_, clen, 0);
}

// Round 7
// 3161.477 us; speedup vs baseline: 1.0198x; 1.0198x over previous
//
#include <hip/hip_runtime.h>
#include <cstdint>
#include <cstddef>

#define B_  128
#define P_  196
#define F_  2048
#define H_  512
#define NF_ 512
#define E_  512
#define V_  10000
#define L_  20
#define T_  19
#define NPAD_ 10112            // 79*128 padded V
#define BH_ (B_ * H_)
#define NBLK_ 256

typedef short s8v __attribute__((ext_vector_type(8)));
typedef float f32x4 __attribute__((ext_vector_type(4)));
typedef unsigned short u16x8 __attribute__((ext_vector_type(8)));

__device__ __forceinline__ float sigf(float x) { return 1.0f / (1.0f + expf(-x)); }
__device__ __forceinline__ ushort f2b(float f) {
    unsigned u = __builtin_bit_cast(unsigned, f);
    u += 0x7fff + ((u >> 16) & 1);          // RNE
    return (ushort)(u >> 16);
}
__device__ __forceinline__ float b2f(ushort h) {
    unsigned u = ((unsigned)h) << 16;
    return __builtin_bit_cast(float, u);
}

// ---- device-wide barrier (non-cooperative): monotone counter, no reset ----
// r5 post-mortem: atomicAdd-RMW polling from 256 blocks at ~50ns period
// serialized the coherence point (~24us/barrier -> kernel 95% idle). Fix:
// one atomicAdd increment per block per barrier, then READ-ONLY
// __hip_atomic_load polling (no cacheline ownership bounce) at ~0.2us
// period. __threadfence gives release/acquire ordering (r5-proven spelling;
// r6's __hip_atomic_fence does not exist in these headers).
// Spin stays BOUNDED: a broken barrier gives wrong results + diagnostics,
// never a GPU hang.
__device__ __forceinline__ void gbar(unsigned* cnt, unsigned target) {
    __syncthreads();
    if (threadIdx.x == 0) {
        __threadfence();
        atomicAdd(cnt, 1u);
        int spins = 0;
        while (__hip_atomic_load(cnt, __ATOMIC_RELAXED, __HIP_MEMORY_SCOPE_AGENT)
                   < target && spins < (1 << 18)) {
            __builtin_amdgcn_s_sleep(8);
            ++spins;
        }
        __threadfence();
    }
    __syncthreads();
}

// ---------------- zero fill (16B granularity) ----------------
__global__ __launch_bounds__(256)
void zero_buf(float4* __restrict__ p, int n16) {
    int i = blockIdx.x * 256 + threadIdx.x;
    if (i < n16) p[i] = make_float4(0.f, 0.f, 0.f, 0.f);
}

// ---------------- cast fp32 matrix -> bf16 (with optional zero row-padding) ---
__global__ __launch_bounds__(256)
void cast_mat(const float* __restrict__ s, ushort* __restrict__ d,
              long long total, int cols, int sld, int srows) {
    long long i4 = ((long long)blockIdx.x * 256 + threadIdx.x) * 4;
    if (i4 >= total) return;
    int n = (int)(i4 / cols);
    int k = (int)(i4 - (long long)n * cols);
    float4 v = make_float4(0.f, 0.f, 0.f, 0.f);
    if (n < srows) v = *(const float4*)(s + (size_t)n * sld + k);
    ushort4 o;
    o.x = f2b(v.x); o.y = f2b(v.y); o.z = f2b(v.z); o.w = f2b(v.w);
    *(ushort4*)(d + i4) = o;
}

// ------- cast with gate-interleave row permutation: row n' -> src row (n'&3)*H + (n'>>2)
__global__ __launch_bounds__(256)
void cast_perm(const float* __restrict__ s, ushort* __restrict__ d,
               int cols, int sld) {
    int idx = blockIdx.x * 256 + threadIdx.x;   // over 2048*cols/4
    int i4 = idx * 4;
    int n = i4 / cols;
    int k = i4 - n * cols;
    int r = (n & 3) * H_ + (n >> 2);
    float4 v = *(const float4*)(s + (size_t)r * sld + k);
    ushort4 o;
    o.x = f2b(v.x); o.y = f2b(v.y); o.z = f2b(v.z); o.w = f2b(v.w);
    *(ushort4*)(d + (size_t)n * cols + k) = o;
}

__global__ __launch_bounds__(256)
void build_bg(const float* __restrict__ bih, const float* __restrict__ bhh,
              float* __restrict__ bg) {
    int n = blockIdx.x * 256 + threadIdx.x;     // 2048
    int r = (n & 3) * H_ + (n >> 2);
    bg[n] = bih[r] + bhh[r];
}

#define NCP_ (2560 + NPAD_)    // combo(2560) + preds cols = 12672 (bias layout only)
__global__ __launch_bounds__(256)
void build_bcp(const float* __restrict__ bha, const float* __restrict__ bfb,
               const float* __restrict__ bfc, float* __restrict__ bcp) {
    int n = blockIdx.x * 256 + threadIdx.x;
    if (n >= NCP_) return;
    float v;
    if (n < 512) v = bha[n];
    else if (n < 2560) v = bfb[n - 512];
    else { int r = n - 2560; v = (r < V_) ? bfc[r] : 0.0f; }
    bcp[n] = v;
}

// ------- fused: mean over P + cast enc -> bf16 (one fp32 pass) -------
__global__ __launch_bounds__(256)
void mean_cast_kernel(const float* __restrict__ enc, ushort* __restrict__ encb,
                      float* __restrict__ feat) {
    int b = blockIdx.x >> 3;
    int f = ((blockIdx.x & 7) << 8) + threadIdx.x;
    const float* p = enc + (size_t)b * P_ * F_ + f;
    ushort* pb = encb + (size_t)b * P_ * F_ + f;
    float s = 0.0f;
    for (int q = 0; q < P_; q++) {
        float v = p[(size_t)q * F_];
        pb[(size_t)q * F_] = f2b(v);
        s += v;
    }
    feat[b * F_ + f] = s * (1.0f / 196.0f);
}

// ---------------- mean only (fallback) ----------------
__global__ __launch_bounds__(256) void mean_kernel(const float* __restrict__ enc,
                                                   float* __restrict__ feat) {
    int b = blockIdx.x >> 3;
    int f = ((blockIdx.x & 7) << 8) + threadIdx.x;
    const float* p = enc + (size_t)b * P_ * F_ + f;
    float s = 0.0f;
    for (int q = 0; q < P_; q++) s += p[(size_t)q * F_];
    feat[b * F_ + f] = s * (1.0f / 196.0f);
}

// ---------------- embedding gather -> bf16 ----------------
__global__ __launch_bounds__(256) void gather_b(const float* __restrict__ emb,
                                                const int* __restrict__ gt,
                                                ushort* __restrict__ embx) {
    int idx = blockIdx.x * 256 + threadIdx.x;
    int i4 = idx * 4;
    int e = i4 & (E_ - 1);
    int bt = i4 >> 9;
    int b = bt / T_, t = bt - b * T_;
    int tok = gt[b * L_ + t];
    float4 v = *(const float4*)(emb + (size_t)tok * E_ + e);
    ushort4 o;
    o.x = f2b(v.x); o.y = f2b(v.y); o.z = f2b(v.z); o.w = f2b(v.w);
    *(ushort4*)(embx + i4) = o;
}

// ---------------- fp32 GEMM (fallback feat_att only) -------------
__global__ __launch_bounds__(256)
void gemm_biasb(const float* __restrict__ A, int lda,
                const float* __restrict__ W, int ldw,
                const float* __restrict__ bias,
                ushort* __restrict__ C, long long ldc,
                int M, int N, int K) {
    __shared__ float As[16][65];
    __shared__ float Ws[16][65];
    const int tid = threadIdx.x;
    const int m0 = blockIdx.y << 6;
    const int n0 = blockIdx.x << 6;
    const int row = tid >> 2;
    const int kq  = (tid & 3) << 2;
    const int ty = tid >> 4, tx = tid & 15;
    float acc[4][4] = {};
    for (int k0 = 0; k0 < K; k0 += 16) {
        float4 av = make_float4(0.f, 0.f, 0.f, 0.f);
        float4 wv = make_float4(0.f, 0.f, 0.f, 0.f);
        int m = m0 + row;
        if (m < M) av = *(const float4*)(A + (size_t)m * lda + k0 + kq);
        int n = n0 + row;
        if (n < N) wv = *(const float4*)(W + (size_t)n * ldw + k0 + kq);
        __syncthreads();
        As[kq + 0][row] = av.x; As[kq + 1][row] = av.y;
        As[kq + 2][row] = av.z; As[kq + 3][row] = av.w;
        Ws[kq + 0][row] = wv.x; Ws[kq + 1][row] = wv.y;
        Ws[kq + 2][row] = wv.z; Ws[kq + 3][row] = wv.w;
        __syncthreads();
#pragma unroll
        for (int k = 0; k < 16; k++) {
            float a[4], w[4];
#pragma unroll
            for (int i = 0; i < 4; i++) a[i] = As[k][(ty << 2) + i];
#pragma unroll
            for (int j = 0; j < 4; j++) w[j] = Ws[k][(tx << 2) + j];
#pragma unroll
            for (int i = 0; i < 4; i++)
#pragma unroll
                for (int j = 0; j < 4; j++)
                    acc[i][j] = fmaf(a[i], w[j], acc[i][j]);
        }
    }
#pragma unroll
    for (int i = 0; i < 4; i++) {
        int m = m0 + (ty << 2) + i;
        if (m >= M) continue;
#pragma unroll
        for (int j = 0; j < 4; j++) {
            int n = n0 + (tx << 2) + j;
            if (n >= N) continue;
            C[(size_t)m * ldc + n] = f2b(acc[i][j] + bias[n]);
        }
    }
}

// ---------------- bf16 MFMA GEMM (standalone, non-scan) ----------------
enum { MEPI_NONE = 0, MEPI_BIAS = 1, MEPI_BIASB = 2, MEPI_PREDS = 3 };

__device__ __forceinline__ void stage_tile(const ushort* __restrict__ g, int ld,
                                           int row0, int k0, ushort* lds,
                                           int rows, int w, int l) {
    int nchunk = rows >> 4;                  // 1024 B (16 rows) per chunk
    for (int c = w; c < nchunk; c += 4) {
        int flat = c * 1024 + l * 16;
        int r = flat >> 6;
        int ce = (flat & 63) >> 1;
        const ushort* gp = g + (size_t)(row0 + r) * ld + (k0 + ce);
        __builtin_amdgcn_global_load_lds(
            (const __attribute__((address_space(1))) void*)gp,
            (__attribute__((address_space(3))) void*)(lds + c * 512),
            16, 0, 0);
    }
}

template <int BM, int EPI, int DUAL, int SWZ = 0>
__global__ __launch_bounds__(256)
void mfma_gemm(const ushort* __restrict__ A1, int lda1,
               const ushort* __restrict__ W1, int ldw1, int K1,
               const ushort* __restrict__ A2, int lda2,
               const ushort* __restrict__ W2, int ldw2, int K2,
               const float* __restrict__ bias, void* __restrict__ Cout, long long ldc,
               void* __restrict__ Cout2,
               int M, int N,
               const int* __restrict__ clen, int tcur) {
    __shared__ ushort As[BM * 32];
    __shared__ ushort Bs[128 * 32];
    const int tid = threadIdx.x;
    const int w = tid >> 6, l = tid & 63;
    const int wr = w >> 1, wc = w & 1;
    constexpr int WM = BM / 2;
    constexpr int AF = WM / 16;
    int bx = blockIdx.x, by = blockIdx.y;
    if (SWZ) {
        const int gx = gridDim.x;
        const int nwg = gx * gridDim.y;
        const int fid = by * gx + bx;
        const int q = nwg >> 3, r = nwg & 7;
        const int xcd = fid & 7, idx = fid >> 3;
        const int nf = (xcd < r ? xcd * (q + 1)
                                : r * (q + 1) + (xcd - r) * q) + idx;
        bx = nf % gx; by = nf / gx;
    }
    const int m0 = by * BM;
    const int n0 = bx * 128;
    const int lrow = l & 15, lk8 = (l >> 4) * 8;
    const int kz = blockIdx.z, nzz = gridDim.z;

    f32x4 acc[AF][4] = {};

    for (int pass = 0; pass < 1 + DUAL; pass++) {
        const ushort* A = pass ? A2 : A1;
        const ushort* W = pass ? W2 : W1;
        const int lda = pass ? lda2 : lda1;
        const int ldw = pass ? ldw2 : ldw1;
        const int K  = pass ? K2 : K1;
        const int chunk = K / nzz;
        const int kbeg = kz * chunk;
        const int kend = kbeg + chunk;
        for (int k0 = kbeg; k0 < kend; k0 += 32) {
            __syncthreads();
            stage_tile(A, lda, m0, k0, As, BM, w, l);
            stage_tile(W, ldw, n0, k0, Bs, 128, w, l);
            __syncthreads();
            s8v af[AF], bf[4];
#pragma unroll
            for (int i = 0; i < AF; i++)
                af[i] = *(const s8v*)(As + (wr * WM + i * 16 + lrow) * 32 + lk8);
#pragma unroll
            for (int j = 0; j < 4; j++)
                bf[j] = *(const s8v*)(Bs + (wc * 64 + j * 16 + lrow) * 32 + lk8);
#pragma unroll
            for (int i = 0; i < AF; i++)
#pragma unroll
                for (int j = 0; j < 4; j++)
                    acc[i][j] = __builtin_amdgcn_mfma_f32_16x16x32_bf16(
                        af[i], bf[j], acc[i][j], 0, 0, 0);
        }
    }

    float* Cz = (float*)Cout + (size_t)kz * (size_t)M * ldc;   // z-partials (MEPI_NONE)
#pragma unroll
    for (int i = 0; i < AF; i++) {
        int rb = m0 + wr * WM + i * 16 + (l >> 4) * 4;
#pragma unroll
        for (int j = 0; j < 4; j++) {
            int n = n0 + wc * 64 + j * 16 + (l & 15);
            if (n >= N) continue;
#pragma unroll
            for (int r = 0; r < 4; r++) {
                int m = rb + r;
                float v = acc[i][j][r];
                if (EPI == MEPI_NONE) {
                    Cz[(size_t)m * ldc + n] = v;
                } else if (EPI == MEPI_BIAS) {
                    ((float*)Cout)[(size_t)m * ldc + n] = v + bias[n];
                } else if (EPI == MEPI_BIASB) {
                    ((ushort*)Cout)[(size_t)m * ldc + n] = f2b(v + bias[n]);
                } else if (EPI == MEPI_PREDS) {
                    if (n < V_) {
                        int bb = m & (B_ - 1);
                        int tt = m >> 7;
                        float mk = (tt < clen[bb] - 1) ? 1.0f : 0.0f;
                        ((float*)Cout)[((size_t)bb * T_ + tt) * (size_t)V_ + n] =
                            (v + bias[n]) * mk;
                    }
                }
            }
        }
    }
}

// ---------------- h0/c0 finalize ----------------
__global__ __launch_bounds__(256)
void h0c0_final(const float* __restrict__ part,   // 4 x B x 1024
                const float* __restrict__ b0,
                const float* __restrict__ g0,
                const float* __restrict__ bt0,
                float* __restrict__ cbuf, ushort* __restrict__ hb) {
    int idx = blockIdx.x * 256 + threadIdx.x;   // B*512
    int b = idx >> 9, j = idx & 511;
    const float rbn = 1.0f / sqrtf(1.0f + 1e-5f);
    float sh = b0[j], sc = b0[j + 512];
    for (int z = 0; z < 4; z++) {
        sh += part[((size_t)z * B_ + b) * 1024 + j];
        sc += part[((size_t)z * B_ + b) * 1024 + j + 512];
    }
    float hv = g0[j] * (sigf(sh) * rbn) + bt0[j];
    float cv = g0[j + 512] * (sigf(sc) * rbn) + bt0[j + 512];
    cbuf[idx] = cv;
    hb[idx] = f2b(hv);
}

// ================= persistent scan megakernel (manual grid barrier) ========
// Grid = 256 blocks x 256 threads. Phases per step t:
//   attn -> bar -> gates(z=4 partials) -> bar -> lstm -> bar -> combo(t+1)
// All phase work is grid-stride so correctness is grid-size independent.
// LDS: 10 KB union — attn {eS[256],red[256],pc[1024]} / GEMM {As 2KB, Bs 8KB}.

struct ScanArgs {
    const void* encv;          // encb (bf16) or enc (fp32)
    const ushort* fattb;
    float* combo;
    const float* Wv;
    float* out_alpha;
    const int* clen;
    ushort* gctxb;
    const ushort* WihF;        // 2048 x 2048 (gate-perm)
    const ushort* Whh;         // 2048 x 512  (gate-perm)
    float* gatesP;             // 4 x B x 2048
    const float* embprojP;     // B*T x 2048
    const float* bg;           // 2048
    float* cbuf;               // B x 512
    ushort* hall;              // (T+1) x B x 512, zero-init
    const ushort* Wcp;         // NCP x 512 (combo rows 0..2559 used here)
    const float* bcp;          // NCP
    unsigned* bar;             // barrier counter (zeroed per launch)
};

// combo unit u in [0, 20*nyb): C[b,0:2560] = h @ Wcp^T + bcp (BM=32)
__device__ __forceinline__ void combo_unit(float* smem, const ushort* hsrc,
                                           const ushort* Wcp, const float* bcp,
                                           float* combo, int u, int tid) {
    ushort* As = (ushort*)smem;            // 32*32
    ushort* Bs = (ushort*)smem + 1024;     // 128*32
    const int w = tid >> 6, l = tid & 63;
    const int wr = w >> 1, wc = w & 1;
    const int lrow = l & 15, lk8 = (l >> 4) * 8;
    const int bx = u % 20, by = u / 20;
    const int m0 = by * 32, n0 = bx * 128;
    f32x4 acc[4] = {};
    for (int k0 = 0; k0 < 512; k0 += 32) {
        __syncthreads();
        stage_tile(hsrc, 512, m0, k0, As, 32, w, l);
        stage_tile(Wcp, 512, n0, k0, Bs, 128, w, l);
        __syncthreads();
        s8v af = *(const s8v*)(As + (wr * 16 + lrow) * 32 + lk8);
        s8v bf[4];
#pragma unroll
        for (int j = 0; j < 4; j++)
            bf[j] = *(const s8v*)(Bs + (wc * 64 + j * 16 + lrow) * 32 + lk8);
#pragma unroll
        for (int j = 0; j < 4; j++)
            acc[j] = __builtin_amdgcn_mfma_f32_16x16x32_bf16(af, bf[j], acc[j], 0, 0, 0);
    }
    const int rb = m0 + wr * 16 + (l >> 4) * 4;
#pragma unroll
    for (int j = 0; j < 4; j++) {
        int n = n0 + wc * 64 + j * 16 + (l & 15);
#pragma unroll
        for (int r = 0; r < 4; r++)
            combo[(size_t)(rb + r) * 2560 + n] = acc[j][r] + bcp[n];
    }
}

// gates unit u in [0, 16*nyb*4): z-partial of [gctx|h] @ [WihF|Whh]^T (BM=32)
__device__ __forceinline__ void gates_unit(float* smem, const ushort* gctxb,
                                           const ushort* WihF, const ushort* hin,
                                           const ushort* Whh, float* gatesP,
                                           int u, int nyb, int tid) {
    ushort* As = (ushort*)smem;
    ushort* Bs = (ushort*)smem + 1024;
    const int w = tid >> 6, l = tid & 63;
    const int wr = w >> 1, wc = w & 1;
    const int lrow = l & 15, lk8 = (l >> 4) * 8;
    const int bx = u & 15;
    const int rem = u >> 4;
    const int by = rem % nyb, kz = rem / nyb;    // kz in 0..3
    const int m0 = by * 32, n0 = bx * 128;
    f32x4 acc[4] = {};
#pragma unroll
    for (int pass = 0; pass < 2; pass++) {
        const ushort* A = pass ? hin : gctxb;
        const ushort* W = pass ? Whh : WihF;
        const int ld = pass ? 512 : 2048;        // lda == ldw both passes
        const int chunk = (pass ? 512 : 2048) >> 2;
        const int kbeg = kz * chunk;
        for (int k0 = kbeg; k0 < kbeg + chunk; k0 += 32) {
            __syncthreads();
            stage_tile(A, ld, m0, k0, As, 32, w, l);
            stage_tile(W, ld, n0, k0, Bs, 128, w, l);
            __syncthreads();
            s8v af = *(const s8v*)(As + (wr * 16 + lrow) * 32 + lk8);
            s8v bf[4];
#pragma unroll
            for (int j = 0; j < 4; j++)
                bf[j] = *(const s8v*)(Bs + (wc * 64 + j * 16 + lrow) * 32 + lk8);
#pragma unroll
            for (int j = 0; j < 4; j++)
                acc[j] = __builtin_amdgcn_mfma_f32_16x16x32_bf16(af, bf[j], acc[j], 0, 0, 0);
        }
    }
    const int rb = m0 + wr * 16 + (l >> 4) * 4;
#pragma unroll
    for (int j = 0; j < 4; j++) {
        int n = n0 + wc * 64 + j * 16 + (l & 15);
#pragma unroll
        for (int r = 0; r < 4; r++)
            gatesP[((size_t)kz * B_ + (rb + r)) * 2048 + n] = acc[j][r];
    }
}

// attn unit: b = active batch, half = f-half
template <int BF>
__device__ __forceinline__ void attn_unit(float* smem, const ScanArgs& a,
                                          int t, int b, int half, int tid) {
    float* eS  = smem;          // 256
    float* red = smem + 256;    // 256
    float* pc  = smem + 512;    // 1024
    const int w = tid >> 6, l = tid & 63;
    const float* hap = a.combo + (size_t)b * 2560;
    float ha8[8], wv8[8];
#pragma unroll
    for (int i = 0; i < 8; i++) { ha8[i] = hap[l * 8 + i]; wv8[i] = a.Wv[l * 8 + i]; }
    eS[tid] = -1e30f;
    __syncthreads();
    const ushort* fab = a.fattb + (size_t)b * P_ * NF_;
    for (int p = w; p < P_; p += 4) {
        const ushort* fp = fab + (size_t)p * NF_ + l * 8;
        ushort4 u0 = *(const ushort4*)fp;
        ushort4 u1 = *(const ushort4*)(fp + 4);
        float s = 0.0f, v;
        v = b2f(u0.x) + ha8[0]; v = v > 0.f ? v : 0.f; s = fmaf(v, wv8[0], s);
        v = b2f(u0.y) + ha8[1]; v = v > 0.f ? v : 0.f; s = fmaf(v, wv8[1], s);
        v = b2f(u0.z) + ha8[2]; v = v > 0.f ? v : 0.f; s = fmaf(v, wv8[2], s);
        v = b2f(u0.w) + ha8[3]; v = v > 0.f ? v : 0.f; s = fmaf(v, wv8[3], s);
        v = b2f(u1.x) + ha8[4]; v = v > 0.f ? v : 0.f; s = fmaf(v, wv8[4], s);
        v = b2f(u1.y) + ha8[5]; v = v > 0.f ? v : 0.f; s = fmaf(v, wv8[5], s);
        v = b2f(u1.z) + ha8[6]; v = v > 0.f ? v : 0.f; s = fmaf(v, wv8[6], s);
        v = b2f(u1.w) + ha8[7]; v = v > 0.f ? v : 0.f; s = fmaf(v, wv8[7], s);
#pragma unroll
        for (int off = 32; off > 0; off >>= 1) s += __shfl_down(s, off, 64);
        if (l == 0) eS[p] = s;
    }
    __syncthreads();
    float ev = eS[tid];
    red[tid] = ev;
    __syncthreads();
    for (int s = 128; s > 0; s >>= 1) {
        if (tid < s) red[tid] = fmaxf(red[tid], red[tid + s]);
        __syncthreads();
    }
    float mx = red[0];
    __syncthreads();
    float ex = expf(ev - mx);
    red[tid] = ex;
    __syncthreads();
    for (int s = 128; s > 0; s >>= 1) {
        if (tid < s) red[tid] += red[tid + s];
        __syncthreads();
    }
    float inv = 1.0f / red[0];
    float aa = ex * inv;
    __syncthreads();
    eS[tid] = aa;                    // alpha now in LDS
    if (half == 0 && tid < P_) {
        a.out_alpha[((size_t)b * T_ + t) * P_ + tid] = aa;  // active => mask 1
    }
    __syncthreads();

    // context: 128 col-threads x 8 cols, two 98-long p-ranges
    int tl = tid & 127;
    int pr = tid >> 7;                       // 0 or 1
    int pp0 = pr * 98;
    int f0 = (half << 10) + tl * 8;
    float s[8] = {};
    if (BF) {
        const ushort* ep = (const ushort*)a.encv + (size_t)b * P_ * F_ +
                           (size_t)pp0 * F_ + f0;
        for (int p = 0; p < 98; p++) {
            u16x8 u = *(const u16x8*)(ep + (size_t)p * F_);
            float al = eS[pp0 + p];
#pragma unroll
            for (int i = 0; i < 8; i++) s[i] = fmaf(al, b2f(u[i]), s[i]);
        }
    } else {
        const float* ep = (const float*)a.encv + (size_t)b * P_ * F_ +
                          (size_t)pp0 * F_ + f0;
        for (int p = 0; p < 98; p++) {
            float4 u0 = *(const float4*)(ep + (size_t)p * F_);
            float4 u1 = *(const float4*)(ep + (size_t)p * F_ + 4);
            float al = eS[pp0 + p];
            s[0] = fmaf(al, u0.x, s[0]); s[1] = fmaf(al, u0.y, s[1]);
            s[2] = fmaf(al, u0.z, s[2]); s[3] = fmaf(al, u0.w, s[3]);
            s[4] = fmaf(al, u1.x, s[4]); s[5] = fmaf(al, u1.y, s[5]);
            s[6] = fmaf(al, u1.z, s[6]); s[7] = fmaf(al, u1.w, s[7]);
        }
    }
    if (pr) {
#pragma unroll
        for (int i = 0; i < 8; i++) pc[tl * 8 + i] = s[i];
    }
    __syncthreads();
    if (!pr) {
        const float* gp = a.combo + (size_t)b * 2560 + 512 + f0;
        float4 ga = *(const float4*)gp;
        float4 gb = *(const float4*)(gp + 4);
        float gv[8] = {ga.x, ga.y, ga.z, ga.w, gb.x, gb.y, gb.z, gb.w};
        ushort o[8];
#pragma unroll
        for (int i = 0; i < 8; i++)
            o[i] = f2b(sigf(gv[i]) * (s[i] + pc[tl * 8 + i]));
        *(u16x8*)(a.gctxb + (size_t)b * F_ + f0) = *(u16x8*)o;
    }
    __syncthreads();                 // smem safe for next grid-stride unit
}

template <int BF>
__global__ __launch_bounds__(256, 2)
void scan_mega(ScanArgs a) {
    const int bid = blockIdx.x;
    const int tid = threadIdx.x;
    const int l = tid & 63;
    __shared__ __align__(16) float smem[2560];   // 10 KB phase union
    const int cl1 = a.clen[l] - 1;
    const int cl2 = a.clen[64 + l] - 1;
    unsigned tgt = 0;

    // combo(0): all 128 batches active (clen >= 2)
    for (int u = bid; u < 80; u += NBLK_)
        combo_unit(smem, a.hall, a.Wcp, a.bcp, a.combo, u, tid);

    for (int t = 0; t < T_; t++) {
        unsigned long long m1 = __ballot(t < cl1);
        unsigned long long m2 = __ballot(t < cl2);
        const int na = __popcll(m1) + __popcll(m2);     // active prefix size
        const int nyb = (na + 31) >> 5;

        tgt += NBLK_; gbar(a.bar, tgt);                 // combo ready
        for (int u = bid; u < 2 * na; u += NBLK_)
            attn_unit<BF>(smem, a, t, u >> 1, u & 1, tid);
        tgt += NBLK_; gbar(a.bar, tgt);                 // gctxb ready
        for (int u = bid; u < 16 * nyb * 4; u += NBLK_)
            gates_unit(smem, a.gctxb, a.WihF, a.hall + (size_t)t * BH_,
                       a.Whh, a.gatesP, u, nyb, tid);
        tgt += NBLK_; gbar(a.bar, tgt);                 // gatesP ready
        for (int u = bid; u < 2 * na; u += NBLK_) {
            int idx = u * 256 + tid;                    // b < na guaranteed
            int b = idx >> 9, j = idx & (H_ - 1);
            int n0 = j * 4;
            float4 g = *(const float4*)(a.embprojP + ((size_t)b * T_ + t) * 2048 + n0);
            float4 bgv = *(const float4*)(a.bg + n0);
            g.x += bgv.x; g.y += bgv.y; g.z += bgv.z; g.w += bgv.w;
#pragma unroll
            for (int z = 0; z < 4; z++) {
                float4 p = *(const float4*)(a.gatesP + ((size_t)z * B_ + b) * 2048 + n0);
                g.x += p.x; g.y += p.y; g.z += p.z; g.w += p.w;
            }
            float cn = sigf(g.y) * a.cbuf[idx] + sigf(g.x) * tanhf(g.z);
            float hn = sigf(g.w) * tanhf(cn);
            a.cbuf[idx] = cn;
            (a.hall + (size_t)(t + 1) * BH_)[idx] = f2b(hn);
        }
        if (t + 1 < T_) {
            tgt += NBLK_; gbar(a.bar, tgt);             // hall[t+1] ready
            unsigned long long n1 = __ballot(t + 1 < cl1);
            unsigned long long n2 = __ballot(t + 1 < cl2);
            const int na2 = __popcll(n1) + __popcll(n2);
            const int nyb2 = (na2 + 31) >> 5;
            for (int u = bid; u < 20 * nyb2; u += NBLK_)
                combo_unit(smem, a.hall + (size_t)(t + 1) * BH_, a.Wcp, a.bcp,
                           a.combo, u, tid);
        }
    }
}

extern "C" void kernel_launch(void* const* d_in, const int* in_sizes, int n_in,
                              void* d_out, int out_size, void* d_ws, size_t ws_size,
                              hipStream_t stream) {
    const float* enc = (const float*)d_in[0];
    const float* emb = (const float*)d_in[1];
    const float* Wfa = (const float*)d_in[2];
    const float* bfa = (const float*)d_in[3];
    const float* Wha = (const float*)d_in[4];
    const float* bha = (const float*)d_in[5];
    const float* Wv  = (const float*)d_in[6];
    const float* Wh0 = (const float*)d_in[8];
    const float* bh0 = (const float*)d_in[9];
    const float* Wc0 = (const float*)d_in[10];
    const float* bc0 = (const float*)d_in[11];
    const float* gh  = (const float*)d_in[12];
    const float* bth = (const float*)d_in[13];
    const float* gc  = (const float*)d_in[14];
    const float* btc = (const float*)d_in[15];
    const float* Wfb = (const float*)d_in[16];
    const float* bfb = (const float*)d_in[17];
    const float* Wih = (const float*)d_in[18];
    const float* Whh = (const float*)d_in[19];
    const float* bih = (const float*)d_in[20];
    const float* bhh = (const float*)d_in[21];
    const float* Wfc = (const float*)d_in[22];
    const float* bfc = (const float*)d_in[23];
    const int* gt   = (const int*)d_in[24];
    const int* clen = (const int*)d_in[25];

    float* out_pred  = (float*)d_out;                       // (B,T,V)
    float* out_alpha = out_pred + (size_t)B_ * T_ * V_;     // (B,T,P)

    char* wp = (char*)d_ws;
    auto alloc = [&](size_t bytes) {
        char* p = wp;
        wp += (bytes + 255) & ~(size_t)255;
        return p;
    };
    float*  feat     = (float*)alloc((size_t)B_ * F_ * 4);
    float*  cbuf     = (float*)alloc((size_t)B_ * H_ * 4);
    float*  combo    = (float*)alloc((size_t)B_ * 2560 * 4);
    float*  embprojP = (float*)alloc((size_t)B_ * T_ * 2048 * 4);
    float*  gatesP   = (float*)alloc((size_t)4 * B_ * 2048 * 4);
    float*  hcpart   = (float*)alloc((size_t)4 * B_ * 1024 * 4);
    float*  bcp      = (float*)alloc((size_t)NCP_ * 4);
    float*  bg       = (float*)alloc(2048 * 4);
    float*  b0comb   = (float*)alloc(1024 * 4);
    float*  g0comb   = (float*)alloc(1024 * 4);
    float*  bt0comb  = (float*)alloc(1024 * 4);
    unsigned* barbuf = (unsigned*)alloc(256);
    ushort* hall     = (ushort*)alloc((size_t)(T_ + 1) * B_ * H_ * 2); // h_0..h_T
    ushort* gctxb    = (ushort*)alloc((size_t)B_ * F_ * 2);
    ushort* embxb    = (ushort*)alloc((size_t)B_ * T_ * E_ * 2);
    ushort* fattb    = (ushort*)alloc((size_t)B_ * P_ * NF_ * 2);
    ushort* featb    = (ushort*)alloc((size_t)B_ * F_ * 2);
    ushort* Wfab     = (ushort*)alloc((size_t)NF_ * F_ * 2);
    ushort* WihEbP   = (ushort*)alloc((size_t)2048 * E_ * 2);
    ushort* WihFbP   = (ushort*)alloc((size_t)2048 * F_ * 2);
    ushort* WhhbP    = (ushort*)alloc((size_t)2048 * H_ * 2);
    ushort* Wcp      = (ushort*)alloc((size_t)NCP_ * H_ * 2);
    ushort* W0comb   = (ushort*)alloc((size_t)1024 * F_ * 2);
    ushort* encb     = (ushort*)alloc((size_t)B_ * P_ * F_ * 2);
    const bool big = ((size_t)(wp - (char*)d_ws) <= ws_size);

    auto castM = [&](const float* s, ushort* d, long long rows, int cols, int sld, int srows) {
        long long total = rows * (long long)cols;
        cast_mat<<<(int)((total + 1023) / 1024), 256, 0, stream>>>(s, d, total, cols, sld, srows);
    };

    // ---- zero-init: hall, out_alpha, barrier counter ----
    {
        int n16h = (int)(((size_t)(T_ + 1) * B_ * H_ * 2) / 16);
        zero_buf<<<(n16h + 255) / 256, 256, 0, stream>>>((float4*)hall, n16h);
        int n16a = (int)(((size_t)B_ * T_ * P_ * 4) / 16);
        zero_buf<<<(n16a + 255) / 256, 256, 0, stream>>>((float4*)out_alpha, n16a);
        zero_buf<<<1, 256, 0, stream>>>((float4*)barbuf, 16);
    }

    // ---- one-time casts / permutes / bias builds ----
    castM(Wfa, Wfab, NF_, F_, F_, NF_);
    cast_perm<<<(2048 * E_) / 1024, 256, 0, stream>>>(Wih, WihEbP, E_, E_ + F_);
    cast_perm<<<(2048 * F_) / 1024, 256, 0, stream>>>(Wih + E_, WihFbP, F_, E_ + F_);
    cast_perm<<<(2048 * H_) / 1024, 256, 0, stream>>>(Whh, WhhbP, H_, H_);
    castM(Wha, Wcp, NF_, H_, H_, NF_);
    castM(Wfb, Wcp + (size_t)512 * H_, F_, H_, H_, F_);
    castM(Wfc, Wcp + (size_t)2560 * H_, NPAD_, H_, H_, V_);
    castM(Wh0, W0comb, H_, F_, F_, H_);
    castM(Wc0, W0comb + (size_t)H_ * F_, H_, F_, F_, H_);
    build_bg<<<2048 / 256, 256, 0, stream>>>(bih, bhh, bg);
    build_bcp<<<(NCP_ + 255) / 256, 256, 0, stream>>>(bha, bfb, bfc, bcp);
    (void)hipMemcpyAsync(b0comb, bh0, H_ * 4, hipMemcpyDeviceToDevice, stream);
    (void)hipMemcpyAsync(b0comb + H_, bc0, H_ * 4, hipMemcpyDeviceToDevice, stream);
    (void)hipMemcpyAsync(g0comb, gh, H_ * 4, hipMemcpyDeviceToDevice, stream);
    (void)hipMemcpyAsync(g0comb + H_, gc, H_ * 4, hipMemcpyDeviceToDevice, stream);
    (void)hipMemcpyAsync(bt0comb, bth, H_ * 4, hipMemcpyDeviceToDevice, stream);
    (void)hipMemcpyAsync(bt0comb + H_, btc, H_ * 4, hipMemcpyDeviceToDevice, stream);

    // ---- init state: fused mean+cast ----
    if (big) mean_cast_kernel<<<B_ * 8, 256, 0, stream>>>(enc, encb, feat);
    else     mean_kernel<<<B_ * 8, 256, 0, stream>>>(enc, feat);
    castM(feat, featb, B_, F_, F_, B_);
    mfma_gemm<32, MEPI_NONE, 0><<<dim3(1024 / 128, B_ / 32, 4), 256, 0, stream>>>(
        featb, F_, W0comb, F_, F_, nullptr, 0, nullptr, 0, 0,
        nullptr, hcpart, 1024, nullptr, B_, 1024, nullptr, 0);
    h0c0_final<<<(B_ * H_) / 256, 256, 0, stream>>>(hcpart, b0comb, g0comb, bt0comb, cbuf, hall);
    gather_b<<<(B_ * T_ * E_) / 1024, 256, 0, stream>>>(emb, gt, embxb);

    // ---- feat_att (bf16 out), XCD-swizzled ----
    if (big) {
        mfma_gemm<128, MEPI_BIASB, 0, 1><<<dim3(NF_ / 128, (B_ * P_) / 128, 1), 256, 0, stream>>>(
            encb, F_, Wfab, F_, F_, nullptr, 0, nullptr, 0, 0,
            bfa, fattb, NF_, nullptr, B_ * P_, NF_, nullptr, 0);
    } else {
        gemm_biasb<<<dim3(NF_ / 64, (B_ * P_) / 64), 256, 0, stream>>>(
            enc, F_, Wfa, F_, bfa, fattb, NF_, B_ * P_, NF_, F_);
    }
    // ---- embprojP = embx @ WihEbP^T (fp32, gate-interleaved cols) ----
    mfma_gemm<128, MEPI_NONE, 0><<<dim3(2048 / 128, (B_ * T_) / 128, 1), 256, 0, stream>>>(
        embxb, E_, WihEbP, E_, E_, nullptr, 0, nullptr, 0, 0,
        nullptr, embprojP, 2048, nullptr, B_ * T_, 2048, nullptr, 0);

    // ---- whole recurrent scan: ONE persistent kernel, manual grid barrier ----
    {
        ScanArgs sa;
        sa.encv = big ? (const void*)encb : (const void*)enc;
        sa.fattb = fattb;
        sa.combo = combo;
        sa.Wv = Wv;
        sa.out_alpha = out_alpha;
        sa.clen = clen;
        sa.gctxb = gctxb;
        sa.WihF = WihFbP;
        sa.Whh = WhhbP;
        sa.gatesP = gatesP;
        sa.embprojP = embprojP;
        sa.bg = bg;
        sa.cbuf = cbuf;
        sa.hall = hall;
        sa.Wcp = Wcp;
        sa.bcp = bcp;
        sa.bar = barbuf;
        if (big) scan_mega<1><<<NBLK_, 256, 0, stream>>>(sa);
        else     scan_mega<0><<<NBLK_, 256, 0, stream>>>(sa);
    }

    // ---- deferred predictions: one big GEMM over all (t,b) rows ----
    // A rows m = t*128 + b -> hall slot t+1; masked rows are zero => output 0.
    mfma_gemm<128, MEPI_PREDS, 0, 1><<<dim3(NPAD_ / 128, (B_ * T_) / 128, 1), 256, 0, stream>>>(
        hall + (size_t)B_ * H_, H_, Wcp + (size_t)2560 * H_, H_, H_,
        nullptr, 0, nullptr, 0, 0,
        bcp + 2560, out_pred, V_, nullptr, B_ * T_, NPAD_, clen, 0);
}

// Round 8
// 1885.154 us; speedup vs baseline: 1.7102x; 1.6770x over previous
//
#include <hip/hip_runtime.h>
#include <cstdint>
#include <cstddef>

#define B_  128
#define P_  196
#define F_  2048
#define H_  512
#define NF_ 512
#define E_  512
#define V_  10000
#define L_  20
#define T_  19
#define NPAD_ 10112            // 79*128 padded V
#define NCP_ (2560 + NPAD_)    // combo(2560) + preds cols = 12672

typedef short s8v __attribute__((ext_vector_type(8)));
typedef float f32x4 __attribute__((ext_vector_type(4)));
typedef unsigned short u16x8 __attribute__((ext_vector_type(8)));

__device__ __forceinline__ float sigf(float x) { return 1.0f / (1.0f + expf(-x)); }
__device__ __forceinline__ ushort f2b(float f) {
    unsigned u = __builtin_bit_cast(unsigned, f);
    u += 0x7fff + ((u >> 16) & 1);          // RNE
    return (ushort)(u >> 16);
}
__device__ __forceinline__ float b2f(ushort h) {
    unsigned u = ((unsigned)h) << 16;
    return __builtin_bit_cast(float, u);
}

// ---------------- fused zero fill of two buffers (16B granularity) ----------
__global__ __launch_bounds__(256)
void zero2(float4* __restrict__ a, int na, float4* __restrict__ b, int nb) {
    int i = blockIdx.x * 256 + threadIdx.x;
    float4 z = make_float4(0.f, 0.f, 0.f, 0.f);
    if (i < na) a[i] = z;
    else { int k = i - na; if (k < nb) b[k] = z; }
}

// ---------------- cast fp32 matrix -> bf16 (fallback path only) -------------
__global__ __launch_bounds__(256)
void cast_mat(const float* __restrict__ s, ushort* __restrict__ d,
              long long total, int cols, int sld, int srows) {
    long long i4 = ((long long)blockIdx.x * 256 + threadIdx.x) * 4;
    if (i4 >= total) return;
    int n = (int)(i4 / cols);
    int k = (int)(i4 - (long long)n * cols);
    float4 v = make_float4(0.f, 0.f, 0.f, 0.f);
    if (n < srows) v = *(const float4*)(s + (size_t)n * sld + k);
    ushort4 o;
    o.x = f2b(v.x); o.y = f2b(v.y); o.z = f2b(v.z); o.w = f2b(v.w);
    *(ushort4*)(d + i4) = o;
}

// ---------------- ALL one-time weight casts in ONE launch -------------------
// jobs: plain cast (optional zero row-pad) or gate-interleave row permutation
// (row n' -> src row (n'&3)*H + (n'>>2)).
struct CastJob {
    const float* s; ushort* d;
    int cols, sld, srows, perm;
    long long total;           // elements
    int blkBase;               // first block of this job
};
struct CastJobs { CastJob j[9]; };

__global__ __launch_bounds__(256)
void cast_multi(CastJobs a) {
    int blk = blockIdx.x;
    int ji = 0;
#pragma unroll
    for (int i = 1; i < 9; i++) if (blk >= a.j[i].blkBase) ji = i;
    const CastJob J = a.j[ji];
    long long i4 = ((long long)(blk - J.blkBase) * 256 + threadIdx.x) * 4;
    if (i4 >= J.total) return;
    int n = (int)(i4 / J.cols);
    int k = (int)(i4 - (long long)n * J.cols);
    float4 v = make_float4(0.f, 0.f, 0.f, 0.f);
    if (J.perm) {
        int r = (n & 3) * H_ + (n >> 2);
        v = *(const float4*)(J.s + (size_t)r * J.sld + k);
    } else if (n < J.srows) {
        v = *(const float4*)(J.s + (size_t)n * J.sld + k);
    }
    ushort4 o;
    o.x = f2b(v.x); o.y = f2b(v.y); o.z = f2b(v.z); o.w = f2b(v.w);
    *(ushort4*)(J.d + i4) = o;
}

// ---------------- all small bias/vector builds in ONE launch ----------------
__global__ __launch_bounds__(256)
void small_prep(const float* __restrict__ bih, const float* __restrict__ bhh,
                const float* __restrict__ bha, const float* __restrict__ bfb,
                const float* __restrict__ bfc,
                const float* __restrict__ bh0, const float* __restrict__ bc0,
                const float* __restrict__ gh,  const float* __restrict__ gc,
                const float* __restrict__ bth, const float* __restrict__ btc,
                float* __restrict__ bg, float* __restrict__ bcp,
                float* __restrict__ b0comb, float* __restrict__ g0comb,
                float* __restrict__ bt0comb) {
    int n = blockIdx.x * 256 + threadIdx.x;
    if (n < 2048) {
        int r = (n & 3) * H_ + (n >> 2);
        bg[n] = bih[r] + bhh[r];
    }
    int m = n - 2048;
    if (m >= 0 && m < NCP_) {
        float v;
        if (m < 512) v = bha[m];
        else if (m < 2560) v = bfb[m - 512];
        else { int r = m - 2560; v = (r < V_) ? bfc[r] : 0.0f; }
        bcp[m] = v;
    }
    int p = n - 2048 - NCP_;
    if (p >= 0 && p < 512) {
        b0comb[p] = bh0[p]; g0comb[p] = gh[p]; bt0comb[p] = bth[p];
    } else if (p >= 512 && p < 1024) {
        int q = p - 512;
        b0comb[p] = bc0[q]; g0comb[p] = gc[q]; bt0comb[p] = btc[q];
    }
}

// ------- fused: mean over P + cast enc -> bf16 + featb (one fp32 pass) ------
__global__ __launch_bounds__(256)
void mean_cast_kernel(const float* __restrict__ enc, ushort* __restrict__ encb,
                      float* __restrict__ feat, ushort* __restrict__ featb) {
    int b = blockIdx.x >> 3;
    int f = ((blockIdx.x & 7) << 8) + threadIdx.x;
    const float* p = enc + (size_t)b * P_ * F_ + f;
    ushort* pb = encb + (size_t)b * P_ * F_ + f;
    float s = 0.0f;
    for (int q = 0; q < P_; q++) {
        float v = p[(size_t)q * F_];
        pb[(size_t)q * F_] = f2b(v);
        s += v;
    }
    float mv = s * (1.0f / 196.0f);
    feat[b * F_ + f] = mv;
    featb[b * F_ + f] = f2b(mv);
}

// ---------------- mean only (fallback) ----------------
__global__ __launch_bounds__(256) void mean_kernel(const float* __restrict__ enc,
                                                   float* __restrict__ feat) {
    int b = blockIdx.x >> 3;
    int f = ((blockIdx.x & 7) << 8) + threadIdx.x;
    const float* p = enc + (size_t)b * P_ * F_ + f;
    float s = 0.0f;
    for (int q = 0; q < P_; q++) s += p[(size_t)q * F_];
    feat[b * F_ + f] = s * (1.0f / 196.0f);
}

// ---------------- embedding gather -> bf16 ----------------
__global__ __launch_bounds__(256) void gather_b(const float* __restrict__ emb,
                                                const int* __restrict__ gt,
                                                ushort* __restrict__ embx) {
    int idx = blockIdx.x * 256 + threadIdx.x;
    int i4 = idx * 4;
    int e = i4 & (E_ - 1);
    int bt = i4 >> 9;
    int b = bt / T_, t = bt - b * T_;
    int tok = gt[b * L_ + t];
    float4 v = *(const float4*)(emb + (size_t)tok * E_ + e);
    ushort4 o;
    o.x = f2b(v.x); o.y = f2b(v.y); o.z = f2b(v.z); o.w = f2b(v.w);
    *(ushort4*)(embx + i4) = o;
}

// ---------------- fp32 GEMM (fallback feat_att only) -------------
__global__ __launch_bounds__(256)
void gemm_biasb(const float* __restrict__ A, int lda,
                const float* __restrict__ W, int ldw,
                const float* __restrict__ bias,
                ushort* __restrict__ C, long long ldc,
                int M, int N, int K) {
    __shared__ float As[16][65];
    __shared__ float Ws[16][65];
    const int tid = threadIdx.x;
    const int m0 = blockIdx.y << 6;
    const int n0 = blockIdx.x << 6;
    const int row = tid >> 2;
    const int kq  = (tid & 3) << 2;
    const int ty = tid >> 4, tx = tid & 15;
    float acc[4][4] = {};
    for (int k0 = 0; k0 < K; k0 += 16) {
        float4 av = make_float4(0.f, 0.f, 0.f, 0.f);
        float4 wv = make_float4(0.f, 0.f, 0.f, 0.f);
        int m = m0 + row;
        if (m < M) av = *(const float4*)(A + (size_t)m * lda + k0 + kq);
        int n = n0 + row;
        if (n < N) wv = *(const float4*)(W + (size_t)n * ldw + k0 + kq);
        __syncthreads();
        As[kq + 0][row] = av.x; As[kq + 1][row] = av.y;
        As[kq + 2][row] = av.z; As[kq + 3][row] = av.w;
        Ws[kq + 0][row] = wv.x; Ws[kq + 1][row] = wv.y;
        Ws[kq + 2][row] = wv.z; Ws[kq + 3][row] = wv.w;
        __syncthreads();
#pragma unroll
        for (int k = 0; k < 16; k++) {
            float a[4], w[4];
#pragma unroll
            for (int i = 0; i < 4; i++) a[i] = As[k][(ty << 2) + i];
#pragma unroll
            for (int j = 0; j < 4; j++) w[j] = Ws[k][(tx << 2) + j];
#pragma unroll
            for (int i = 0; i < 4; i++)
#pragma unroll
                for (int j = 0; j < 4; j++)
                    acc[i][j] = fmaf(a[i], w[j], acc[i][j]);
        }
    }
#pragma unroll
    for (int i = 0; i < 4; i++) {
        int m = m0 + (ty << 2) + i;
        if (m >= M) continue;
#pragma unroll
        for (int j = 0; j < 4; j++) {
            int n = n0 + (tx << 2) + j;
            if (n >= N) continue;
            C[(size_t)m * ldc + n] = f2b(acc[i][j] + bias[n]);
        }
    }
}

// ---------------- bf16 MFMA GEMM ----------------
enum { MEPI_NONE = 0, MEPI_BIAS = 1, MEPI_BIASB = 2, MEPI_PREDS = 3 };

__device__ __forceinline__ void stage_tile(const ushort* __restrict__ g, int ld,
                                           int row0, int k0, ushort* lds,
                                           int rows, int w, int l) {
    int nchunk = rows >> 4;                  // 1024 B (16 rows) per chunk
    for (int c = w; c < nchunk; c += 4) {
        int flat = c * 1024 + l * 16;
        int r = flat >> 6;
        int ce = (flat & 63) >> 1;
        const ushort* gp = g + (size_t)(row0 + r) * ld + (k0 + ce);
        __builtin_amdgcn_global_load_lds(
            (const __attribute__((address_space(1))) void*)gp,
            (__attribute__((address_space(3))) void*)(lds + c * 512),
            16, 0, 0);
    }
}

template <int BM, int EPI, int DUAL, int SWZ = 0, int MSK = 0>
__global__ __launch_bounds__(256)
void mfma_gemm(const ushort* __restrict__ A1, int lda1,
               const ushort* __restrict__ W1, int ldw1, int K1,
               const ushort* __restrict__ A2, int lda2,
               const ushort* __restrict__ W2, int ldw2, int K2,
               const float* __restrict__ bias, void* __restrict__ Cout, long long ldc,
               void* __restrict__ Cout2,
               int M, int N,
               const int* __restrict__ clen, int tcur) {
    __shared__ ushort As[BM * 32];
    __shared__ ushort Bs[128 * 32];
    const int tid = threadIdx.x;
    const int w = tid >> 6, l = tid & 63;
    const int wr = w >> 1, wc = w & 1;
    constexpr int WM = BM / 2;
    constexpr int AF = WM / 16;
    int bx = blockIdx.x, by = blockIdx.y;
    if (SWZ) {
        // bijective XCD-chunked remap (8 XCDs)
        const int gx = gridDim.x;
        const int nwg = gx * gridDim.y;
        const int fid = by * gx + bx;
        const int q = nwg >> 3, r = nwg & 7;
        const int xcd = fid & 7, idx = fid >> 3;
        const int nf = (xcd < r ? xcd * (q + 1)
                                : r * (q + 1) + (xcd - r) * q) + idx;
        bx = nf % gx; by = nf / gx;
    }
    if (MSK) {
        // rows of this block are batches; skip if ALL are masked at tcur.
        int cl = clen[by * BM + (l & (BM - 1))];
        if (!__any(tcur < cl - 1)) return;
    }
    const int m0 = by * BM;
    const int n0 = bx * 128;
    const int lrow = l & 15, lk8 = (l >> 4) * 8;
    const int kz = blockIdx.z, nzz = gridDim.z;

    f32x4 acc[AF][4] = {};

    for (int pass = 0; pass < 1 + DUAL; pass++) {
        const ushort* A = pass ? A2 : A1;
        const ushort* W = pass ? W2 : W1;
        const int lda = pass ? lda2 : lda1;
        const int ldw = pass ? ldw2 : ldw1;
        const int K  = pass ? K2 : K1;
        const int chunk = K / nzz;
        const int kbeg = kz * chunk;
        const int kend = kbeg + chunk;
        for (int k0 = kbeg; k0 < kend; k0 += 32) {
            __syncthreads();
            stage_tile(A, lda, m0, k0, As, BM, w, l);
            stage_tile(W, ldw, n0, k0, Bs, 128, w, l);
            __syncthreads();
            s8v af[AF], bf[4];
#pragma unroll
            for (int i = 0; i < AF; i++)
                af[i] = *(const s8v*)(As + (wr * WM + i * 16 + lrow) * 32 + lk8);
#pragma unroll
            for (int j = 0; j < 4; j++)
                bf[j] = *(const s8v*)(Bs + (wc * 64 + j * 16 + lrow) * 32 + lk8);
#pragma unroll
            for (int i = 0; i < AF; i++)
#pragma unroll
                for (int j = 0; j < 4; j++)
                    acc[i][j] = __builtin_amdgcn_mfma_f32_16x16x32_bf16(
                        af[i], bf[j], acc[i][j], 0, 0, 0);
        }
    }

    float* Cz = (float*)Cout + (size_t)kz * (size_t)M * ldc;   // z-partials (MEPI_NONE)
#pragma unroll
    for (int i = 0; i < AF; i++) {
        int rb = m0 + wr * WM + i * 16 + (l >> 4) * 4;
#pragma unroll
        for (int j = 0; j < 4; j++) {
            int n = n0 + wc * 64 + j * 16 + (l & 15);
            if (n >= N) continue;
#pragma unroll
            for (int r = 0; r < 4; r++) {
                int m = rb + r;
                float v = acc[i][j][r];
                if (EPI == MEPI_NONE) {
                    Cz[(size_t)m * ldc + n] = v;
                } else if (EPI == MEPI_BIAS) {
                    ((float*)Cout)[(size_t)m * ldc + n] = v + bias[n];
                } else if (EPI == MEPI_BIASB) {
                    ((ushort*)Cout)[(size_t)m * ldc + n] = f2b(v + bias[n]);
                } else if (EPI == MEPI_PREDS) {
                    // deferred predictions: rows m = t*128 + b over hall[1..T]
                    if (n < V_) {
                        int bb = m & (B_ - 1);
                        int tt = m >> 7;
                        float mk = (tt < clen[bb] - 1) ? 1.0f : 0.0f;
                        ((float*)Cout)[((size_t)bb * T_ + tt) * (size_t)V_ + n] =
                            (v + bias[n]) * mk;
                    }
                }
            }
        }
    }
}

// ---------------- h0/c0 finalize ----------------
__global__ __launch_bounds__(256)
void h0c0_final(const float* __restrict__ part,   // 4 x B x 1024
                const float* __restrict__ b0,
                const float* __restrict__ g0,
                const float* __restrict__ bt0,
                float* __restrict__ cbuf, ushort* __restrict__ hb) {
    int idx = blockIdx.x * 256 + threadIdx.x;   // B*512
    int b = idx >> 9, j = idx & 511;
    const float rbn = 1.0f / sqrtf(1.0f + 1e-5f);
    float sh = b0[j], sc = b0[j + 512];
    for (int z = 0; z < 4; z++) {
        sh += part[((size_t)z * B_ + b) * 1024 + j];
        sc += part[((size_t)z * B_ + b) * 1024 + j + 512];
    }
    float hv = g0[j] * (sigf(sh) * rbn) + bt0[j];
    float cv = g0[j + 512] * (sigf(sc) * rbn) + bt0[j + 512];
    cbuf[idx] = cv;
    hb[idx] = f2b(hv);
}

// ---- fused attention score + softmax + context + input-gate ----
template <int BF>
__global__ __launch_bounds__(256)
void attn_ctx(const void* __restrict__ encv, const ushort* __restrict__ fa,
              const float* __restrict__ combo, const float* __restrict__ Wv,
              float* __restrict__ alphas_out, const int* __restrict__ clen,
              ushort* __restrict__ gctxb, int t) {
    int b = blockIdx.x >> 1;
    if (t >= clen[b] - 1) return;            // masked batch: all outputs dead
    int half = blockIdx.x & 1;
    int tid = threadIdx.x;
    int w = tid >> 6, l = tid & 63;
    __shared__ float eS[256];
    __shared__ float red[256];
    __shared__ float pc[128 * 8];
    const float* hap = combo + (size_t)b * 2560;
    float ha8[8], wv8[8];
#pragma unroll
    for (int i = 0; i < 8; i++) { ha8[i] = hap[l * 8 + i]; wv8[i] = Wv[l * 8 + i]; }
    eS[tid] = -1e30f;
    __syncthreads();
    const ushort* fab = fa + (size_t)b * P_ * NF_;
    for (int p = w; p < P_; p += 4) {
        const ushort* fp = fab + (size_t)p * NF_ + l * 8;
        ushort4 u0 = *(const ushort4*)fp;
        ushort4 u1 = *(const ushort4*)(fp + 4);
        float s = 0.0f, v;
        v = b2f(u0.x) + ha8[0]; v = v > 0.f ? v : 0.f; s = fmaf(v, wv8[0], s);
        v = b2f(u0.y) + ha8[1]; v = v > 0.f ? v : 0.f; s = fmaf(v, wv8[1], s);
        v = b2f(u0.z) + ha8[2]; v = v > 0.f ? v : 0.f; s = fmaf(v, wv8[2], s);
        v = b2f(u0.w) + ha8[3]; v = v > 0.f ? v : 0.f; s = fmaf(v, wv8[3], s);
        v = b2f(u1.x) + ha8[4]; v = v > 0.f ? v : 0.f; s = fmaf(v, wv8[4], s);
        v = b2f(u1.y) + ha8[5]; v = v > 0.f ? v : 0.f; s = fmaf(v, wv8[5], s);
        v = b2f(u1.z) + ha8[6]; v = v > 0.f ? v : 0.f; s = fmaf(v, wv8[6], s);
        v = b2f(u1.w) + ha8[7]; v = v > 0.f ? v : 0.f; s = fmaf(v, wv8[7], s);
#pragma unroll
        for (int off = 32; off > 0; off >>= 1) s += __shfl_down(s, off, 64);
        if (l == 0) eS[p] = s;
    }
    __syncthreads();
    float ev = eS[tid];
    red[tid] = ev;
    __syncthreads();
    for (int s = 128; s > 0; s >>= 1) {
        if (tid < s) red[tid] = fmaxf(red[tid], red[tid + s]);
        __syncthreads();
    }
    float mx = red[0];
    __syncthreads();
    float ex = expf(ev - mx);
    red[tid] = ex;
    __syncthreads();
    for (int s = 128; s > 0; s >>= 1) {
        if (tid < s) red[tid] += red[tid + s];
        __syncthreads();
    }
    float inv = 1.0f / red[0];
    float a = ex * inv;
    __syncthreads();
    eS[tid] = a;                     // alpha now in LDS
    if (half == 0 && tid < P_) {
        alphas_out[((size_t)b * T_ + t) * P_ + tid] = a;   // active => mask = 1
    }
    __syncthreads();

    // context: 128 col-threads x 8 cols, two 98-long p-ranges
    int tl = tid & 127;
    int pr = tid >> 7;                       // 0 or 1
    int pp0 = pr * 98;
    int f0 = (half << 10) + tl * 8;
    float s[8] = {};
    if (BF) {
        const ushort* ep = (const ushort*)encv + (size_t)b * P_ * F_ +
                           (size_t)pp0 * F_ + f0;
        for (int p = 0; p < 98; p++) {
            u16x8 u = *(const u16x8*)(ep + (size_t)p * F_);
            float al = eS[pp0 + p];
#pragma unroll
            for (int i = 0; i < 8; i++) s[i] = fmaf(al, b2f(u[i]), s[i]);
        }
    } else {
        const float* ep = (const float*)encv + (size_t)b * P_ * F_ +
                          (size_t)pp0 * F_ + f0;
        for (int p = 0; p < 98; p++) {
            float4 u0 = *(const float4*)(ep + (size_t)p * F_);
            float4 u1 = *(const float4*)(ep + (size_t)p * F_ + 4);
            float al = eS[pp0 + p];
            s[0] = fmaf(al, u0.x, s[0]); s[1] = fmaf(al, u0.y, s[1]);
            s[2] = fmaf(al, u0.z, s[2]); s[3] = fmaf(al, u0.w, s[3]);
            s[4] = fmaf(al, u1.x, s[4]); s[5] = fmaf(al, u1.y, s[5]);
            s[6] = fmaf(al, u1.z, s[6]); s[7] = fmaf(al, u1.w, s[7]);
        }
    }
    if (pr) {
#pragma unroll
        for (int i = 0; i < 8; i++) pc[tl * 8 + i] = s[i];
    }
    __syncthreads();
    if (!pr) {
        const float* gp = combo + (size_t)b * 2560 + 512 + f0;
        float4 ga = *(const float4*)gp;
        float4 gb = *(const float4*)(gp + 4);
        float gv[8] = {ga.x, ga.y, ga.z, ga.w, gb.x, gb.y, gb.z, gb.w};
        ushort o[8];
#pragma unroll
        for (int i = 0; i < 8; i++)
            o[i] = f2b(sigf(gv[i]) * (s[i] + pc[tl * 8 + i]));
        *(u16x8*)(gctxb + (size_t)b * F_ + f0) = *(u16x8*)o;
    }
}

// ---- LSTM pointwise over gate-interleaved z-partials ----
__global__ __launch_bounds__(256)
void lstm_perm(const float* __restrict__ gatesP,   // 4 x B x 2048 (permuted)
               const float* __restrict__ embprojP, // B*T x 2048 (permuted)
               const float* __restrict__ bg,       // 2048 (permuted bih+bhh)
               const int* __restrict__ clen,
               float* __restrict__ cbuf, ushort* __restrict__ hout, int t) {
    int idx = blockIdx.x * 256 + threadIdx.x;   // B*H
    int b = idx >> 9, j = idx & (H_ - 1);
    if (t >= clen[b] - 1) return;            // masked: hout stays 0, cbuf dead
    int n0 = j * 4;
    float4 g = *(const float4*)(embprojP + ((size_t)b * T_ + t) * 2048 + n0);
    float4 bgv = *(const float4*)(bg + n0);
    g.x += bgv.x; g.y += bgv.y; g.z += bgv.z; g.w += bgv.w;
#pragma unroll
    for (int z = 0; z < 4; z++) {
        float4 p = *(const float4*)(gatesP + ((size_t)z * B_ + b) * 2048 + n0);
        g.x += p.x; g.y += p.y; g.z += p.z; g.w += p.w;
    }
    float cn = sigf(g.y) * cbuf[idx] + sigf(g.x) * tanhf(g.z);
    float hn = sigf(g.w) * tanhf(cn);
    cbuf[idx] = cn;
    hout[idx] = f2b(hn);
}

extern "C" void kernel_launch(void* const* d_in, const int* in_sizes, int n_in,
                              void* d_out, int out_size, void* d_ws, size_t ws_size,
                              hipStream_t stream) {
    const float* enc = (const float*)d_in[0];
    const float* emb = (const float*)d_in[1];
    const float* Wfa = (const float*)d_in[2];
    const float* bfa = (const float*)d_in[3];
    const float* Wha = (const float*)d_in[4];
    const float* bha = (const float*)d_in[5];
    const float* Wv  = (const float*)d_in[6];
    const float* Wh0 = (const float*)d_in[8];
    const float* bh0 = (const float*)d_in[9];
    const float* Wc0 = (const float*)d_in[10];
    const float* bc0 = (const float*)d_in[11];
    const float* gh  = (const float*)d_in[12];
    const float* bth = (const float*)d_in[13];
    const float* gc  = (const float*)d_in[14];
    const float* btc = (const float*)d_in[15];
    const float* Wfb = (const float*)d_in[16];
    const float* bfb = (const float*)d_in[17];
    const float* Wih = (const float*)d_in[18];
    const float* Whh = (const float*)d_in[19];
    const float* bih = (const float*)d_in[20];
    const float* bhh = (const float*)d_in[21];
    const float* Wfc = (const float*)d_in[22];
    const float* bfc = (const float*)d_in[23];
    const int* gt   = (const int*)d_in[24];
    const int* clen = (const int*)d_in[25];

    float* out_pred  = (float*)d_out;                       // (B,T,V)
    float* out_alpha = out_pred + (size_t)B_ * T_ * V_;     // (B,T,P)

    char* wp = (char*)d_ws;
    auto alloc = [&](size_t bytes) {
        char* p = wp;
        wp += (bytes + 255) & ~(size_t)255;
        return p;
    };
    float*  feat     = (float*)alloc((size_t)B_ * F_ * 4);
    float*  cbuf     = (float*)alloc((size_t)B_ * H_ * 4);
    float*  combo    = (float*)alloc((size_t)B_ * 2560 * 4);
    float*  embprojP = (float*)alloc((size_t)B_ * T_ * 2048 * 4);
    float*  gatesP   = (float*)alloc((size_t)4 * B_ * 2048 * 4);
    float*  hcpart   = (float*)alloc((size_t)4 * B_ * 1024 * 4);
    float*  bcp      = (float*)alloc((size_t)NCP_ * 4);
    float*  bg       = (float*)alloc(2048 * 4);
    float*  b0comb   = (float*)alloc(1024 * 4);
    float*  g0comb   = (float*)alloc(1024 * 4);
    float*  bt0comb  = (float*)alloc(1024 * 4);
    ushort* hall     = (ushort*)alloc((size_t)(T_ + 1) * B_ * H_ * 2); // h_0..h_T
    ushort* gctxb    = (ushort*)alloc((size_t)B_ * F_ * 2);
    ushort* embxb    = (ushort*)alloc((size_t)B_ * T_ * E_ * 2);
    ushort* fattb    = (ushort*)alloc((size_t)B_ * P_ * NF_ * 2);
    ushort* featb    = (ushort*)alloc((size_t)B_ * F_ * 2);
    ushort* Wfab     = (ushort*)alloc((size_t)NF_ * F_ * 2);
    ushort* WihEbP   = (ushort*)alloc((size_t)2048 * E_ * 2);
    ushort* WihFbP   = (ushort*)alloc((size_t)2048 * F_ * 2);
    ushort* WhhbP    = (ushort*)alloc((size_t)2048 * H_ * 2);
    ushort* Wcp      = (ushort*)alloc((size_t)NCP_ * H_ * 2);
    ushort* W0comb   = (ushort*)alloc((size_t)1024 * F_ * 2);
    ushort* encb     = (ushort*)alloc((size_t)B_ * P_ * F_ * 2);
    const bool big = ((size_t)(wp - (char*)d_ws) <= ws_size);

    // ---- zero-init hall + out_alpha in ONE launch ----
    {
        int na = (int)(((size_t)(T_ + 1) * B_ * H_ * 2) / 16);
        int nb = (int)(((size_t)B_ * T_ * P_ * 4) / 16);
        zero2<<<(na + nb + 255) / 256, 256, 0, stream>>>(
            (float4*)hall, na, (float4*)out_alpha, nb);
    }

    // ---- ALL weight casts/permutes in ONE launch ----
    {
        CastJobs cj;
        auto mk = [](const float* s, ushort* d, long long rows, int cols,
                     int sld, int srows, int perm) {
            CastJob j; j.s = s; j.d = d; j.cols = cols; j.sld = sld;
            j.srows = srows; j.perm = perm; j.total = rows * (long long)cols;
            j.blkBase = 0; return j;
        };
        cj.j[0] = mk(Wfa, Wfab, NF_, F_, F_, NF_, 0);
        cj.j[1] = mk(Wih, WihEbP, 2048, E_, E_ + F_, 2048, 1);
        cj.j[2] = mk(Wih + E_, WihFbP, 2048, F_, E_ + F_, 2048, 1);
        cj.j[3] = mk(Whh, WhhbP, 2048, H_, H_, 2048, 1);
        cj.j[4] = mk(Wha, Wcp, NF_, H_, H_, NF_, 0);
        cj.j[5] = mk(Wfb, Wcp + (size_t)512 * H_, F_, H_, H_, F_, 0);
        cj.j[6] = mk(Wfc, Wcp + (size_t)2560 * H_, NPAD_, H_, H_, V_, 0);
        cj.j[7] = mk(Wh0, W0comb, H_, F_, F_, H_, 0);
        cj.j[8] = mk(Wc0, W0comb + (size_t)H_ * F_, H_, F_, F_, H_, 0);
        int base = 0;
        for (int i = 0; i < 9; i++) {
            cj.j[i].blkBase = base;
            base += (int)((cj.j[i].total + 1023) / 1024);
        }
        cast_multi<<<base, 256, 0, stream>>>(cj);
    }

    // ---- all small bias/vector builds in ONE launch ----
    small_prep<<<(2048 + NCP_ + 1024 + 255) / 256, 256, 0, stream>>>(
        bih, bhh, bha, bfb, bfc, bh0, bc0, gh, gc, bth, btc,
        bg, bcp, b0comb, g0comb, bt0comb);

    // ---- init state: fused mean+cast (+featb direct) ----
    if (big) {
        mean_cast_kernel<<<B_ * 8, 256, 0, stream>>>(enc, encb, feat, featb);
    } else {
        mean_kernel<<<B_ * 8, 256, 0, stream>>>(enc, feat);
        long long total = (long long)B_ * F_;
        cast_mat<<<(int)((total + 1023) / 1024), 256, 0, stream>>>(
            feat, featb, total, F_, F_, B_);
    }
    mfma_gemm<32, MEPI_NONE, 0><<<dim3(1024 / 128, B_ / 32, 4), 256, 0, stream>>>(
        featb, F_, W0comb, F_, F_, nullptr, 0, nullptr, 0, 0,
        nullptr, hcpart, 1024, nullptr, B_, 1024, nullptr, 0);
    h0c0_final<<<(B_ * H_) / 256, 256, 0, stream>>>(hcpart, b0comb, g0comb, bt0comb, cbuf, hall);
    gather_b<<<(B_ * T_ * E_) / 1024, 256, 0, stream>>>(emb, gt, embxb);

    // ---- feat_att (bf16 out), XCD-swizzled ----
    if (big) {
        mfma_gemm<128, MEPI_BIASB, 0, 1><<<dim3(NF_ / 128, (B_ * P_) / 128, 1), 256, 0, stream>>>(
            encb, F_, Wfab, F_, F_, nullptr, 0, nullptr, 0, 0,
            bfa, fattb, NF_, nullptr, B_ * P_, NF_, nullptr, 0);
    } else {
        gemm_biasb<<<dim3(NF_ / 64, (B_ * P_) / 64), 256, 0, stream>>>(
            enc, F_, Wfa, F_, bfa, fattb, NF_, B_ * P_, NF_, F_);
    }
    // ---- embprojP = embx @ WihEbP^T (fp32, gate-interleaved cols) ----
    mfma_gemm<128, MEPI_NONE, 0><<<dim3(2048 / 128, (B_ * T_) / 128, 1), 256, 0, stream>>>(
        embxb, E_, WihEbP, E_, E_, nullptr, 0, nullptr, 0, 0,
        nullptr, embprojP, 2048, nullptr, B_ * T_, 2048, nullptr, 0);

    // ---- combo(0) from h0 (all batches active at t=0 since clen >= 2) ----
    mfma_gemm<32, MEPI_BIAS, 0><<<dim3(2560 / 128, B_ / 32, 1), 256, 0, stream>>>(
        hall, H_, Wcp, H_, H_, nullptr, 0, nullptr, 0, 0,
        bcp, combo, 2560, nullptr, B_, 2560, nullptr, 0);

    // ---- recurrent scan: 4 launches per step; masked-batch work skipped ----
    for (int t = 0; t < T_; t++) {
        ushort* hin  = hall + (size_t)t * B_ * H_;
        ushort* hout = hall + (size_t)(t + 1) * B_ * H_;
        if (big) attn_ctx<1><<<B_ * 2, 256, 0, stream>>>(encb, fattb, combo, Wv,
                                                         out_alpha, clen, gctxb, t);
        else     attn_ctx<0><<<B_ * 2, 256, 0, stream>>>(enc, fattb, combo, Wv,
                                                         out_alpha, clen, gctxb, t);
        // gates partials: z=4, blocks skip when their 32 batches all masked at t
        mfma_gemm<32, MEPI_NONE, 1, 0, 1><<<dim3(2048 / 128, B_ / 32, 4), 256, 0, stream>>>(
            gctxb, F_, WihFbP, F_, F_, hin, H_, WhhbP, H_, H_,
            nullptr, gatesP, 2048, nullptr, B_, 2048, clen, t);
        lstm_perm<<<(B_ * H_) / 256, 256, 0, stream>>>(
            gatesP, embprojP, bg, clen, cbuf, hout, t);
        // combo(t+1): only needed for batches active at t+1
        mfma_gemm<32, MEPI_BIAS, 0, 0, 1><<<dim3(2560 / 128, B_ / 32, 1), 256, 0, stream>>>(
            hout, H_, Wcp, H_, H_, nullptr, 0, nullptr, 0, 0,
            bcp, combo, 2560, nullptr, B_, 2560, clen, t + 1);
    }

    // ---- deferred predictions: one big GEMM over all (t,b) rows ----
    // A rows m = t*128 + b -> hall slot t+1; masked rows are zero => output 0.
    mfma_gemm<128, MEPI_PREDS, 0, 1><<<dim3(NPAD_ / 128, (B_ * T_) / 128, 1), 256, 0, stream>>>(
        hall + (size_t)B_ * H_, H_, Wcp + (size_t)2560 * H_, H_, H_,
        nullptr, 0, nullptr, 0, 0,
        bcp + 2560, out_pred, V_, nullptr, B_ * T_, NPAD_, clen, 0);
}